// Round 11
// baseline (265.846 us; speedup 1.0000x reference)
//
#include <hip/hip_runtime.h>
#include <math.h>

#define DIMX 1024
#define D_STATE 16
#define D_INNER 2048
#define DT_RANK 64
#define B_SZ 2
#define L_SEQ 1024
#define NTOK (B_SZ * L_SEQ)
#define EPSR 1e-5f
#define NC 16          // chunks over sequence
#define LC 64          // steps per chunk
#define NCH (B_SZ * D_INNER)            // 4096 channels
#define NLANE (NCH * D_STATE)           // 65536 (chan,state) pairs
#define LOG2E 1.44269504f

typedef __attribute__((ext_vector_type(8))) short bf16x8;
typedef __attribute__((ext_vector_type(4))) int   i32x4;
typedef __attribute__((ext_vector_type(4))) float f32x4;
typedef __attribute__((ext_vector_type(4))) unsigned short u16x4;

__device__ __forceinline__ unsigned short f2b(float f) {
    unsigned int u = __builtin_bit_cast(unsigned int, f);
    u += 0x7fffu + ((u >> 16) & 1u);          // RNE
    return (unsigned short)(u >> 16);
}
__device__ __forceinline__ float b2f(unsigned short h) {
    unsigned int u = ((unsigned int)h) << 16;
    return __builtin_bit_cast(float, u);
}
__device__ __forceinline__ float lo2f(unsigned int v) {       // low bf16 -> f32
    return __builtin_bit_cast(float, v << 16);
}
__device__ __forceinline__ float hi2f(unsigned int v) {       // high bf16 -> f32
    return __builtin_bit_cast(float, v & 0xffff0000u);
}

// ---------------- f32 -> bf16 conversion ----------------
__global__ void f2b_kernel(const float* __restrict__ in, unsigned short* __restrict__ out, int n4) {
    int i = blockIdx.x * 256 + threadIdx.x;
    if (i < n4) {
        f32x4 v = *(const f32x4*)(in + (size_t)i * 4);
        unsigned short o[4];
#pragma unroll
        for (int j = 0; j < 4; ++j) o[j] = f2b(v[j]);
        *(unsigned long long*)(out + (size_t)i * 4) = *(unsigned long long*)o;
    }
}

// ---------------- RMSNorm ----------------
__global__ void rmsnorm_kernel(const float* __restrict__ x, const float* __restrict__ w,
                               unsigned short* __restrict__ xnb) {
    int row = blockIdx.x;
    const float* xr = x + (size_t)row * DIMX;
    unsigned short* outr = xnb + (size_t)row * DIMX;
    int t = threadIdx.x;
    float v[4];
    float ss = 0.f;
#pragma unroll
    for (int i = 0; i < 4; ++i) { v[i] = xr[t + i * 256]; ss += v[i] * v[i]; }
#pragma unroll
    for (int off = 32; off > 0; off >>= 1) ss += __shfl_down(ss, off);
    __shared__ float red[4];
    if ((t & 63) == 0) red[t >> 6] = ss;
    __syncthreads();
    float tot = red[0] + red[1] + red[2] + red[3];
    float scale = rsqrtf(tot * (1.f / DIMX) + EPSR);
#pragma unroll
    for (int i = 0; i < 4; ++i) outr[t + i * 256] = f2b(v[i] * scale * w[t + i * 256]);
}

// ---------------- bf16 64x64-tile transpose: dst[C][R] = src[R][C]^T ----------------
__global__ __launch_bounds__(256) void transpose_bf16(
    const unsigned short* __restrict__ src, unsigned short* __restrict__ dst,
    int R, int C) {
    __shared__ unsigned int xt[64 * 65];
    const int r0 = blockIdx.y * 64, c0 = blockIdx.x * 64;
    const int tid = threadIdx.x;
#pragma unroll
    for (int i = 0; i < 2; ++i) {
        int chunk = tid + i * 256;
        int r = chunk >> 3, cc = (chunk & 7) * 8;
        i32x4 v = *(const i32x4*)(src + (size_t)(r0 + r) * C + c0 + cc);
        const unsigned short* vs = (const unsigned short*)&v;
#pragma unroll
        for (int j = 0; j < 8; ++j) xt[(cc + j) * 65 + r] = vs[j];
    }
    __syncthreads();
#pragma unroll
    for (int i = 0; i < 2; ++i) {
        int chunk = tid + i * 256;
        int c = chunk >> 3, rr = (chunk & 7) * 8;
        unsigned short o[8];
#pragma unroll
        for (int j = 0; j < 8; ++j) o[j] = (unsigned short)xt[c * 65 + rr + j];
        *(i32x4*)(dst + (size_t)(c0 + c) * R + r0 + rr) = *(const i32x4*)o;
    }
}

// ---------------- bf16 MFMA GEMM: C[M,N] = A[M,K] * B[N,K]^T (A,B bf16 row-major) ----------------
// EPI 0: row-major f32 partial store (split-K via blockIdx.z plane offset)
// EPI 1: dt_proj: delta = softplus(acc+bias[col]);
//        C (u32) <- pack(bf16(delta), bf16(delta*u)) [transposed]; C2 (bf16) <- u*aux[col]
// EPI 3: in_proj: col<2048 -> C bf16 transposed (xi_T), else C2 bf16 transposed (z_b)
template <int EPI>
__global__ __launch_bounds__(256) void gemm_mfma(
    const unsigned short* __restrict__ A, const unsigned short* __restrict__ B,
    void* __restrict__ C, void* __restrict__ C2,
    int M, int N, int K, int lda, int ldb, int ldc,
    const float* __restrict__ bias, const float* __restrict__ res,
    const float* __restrict__ aux) {
    __shared__ unsigned short As[128 * 40];
    __shared__ unsigned short Bs[128 * 40];
    const int tid = threadIdx.x;
    const int m0 = blockIdx.y * 128, n0 = blockIdx.x * 128;
    const int lane = tid & 63, wave = tid >> 6;
    const int wr = (wave >> 1) * 64, wc = (wave & 1) * 64;
    const int fr = lane & 15, fk = (lane >> 4) * 8;
    const int kspan = K / gridDim.z;
    const int kb = blockIdx.z * kspan;
    f32x4 acc[4][4] = {};
    for (int k0 = kb; k0 < kb + kspan; k0 += 32) {
#pragma unroll
        for (int i = 0; i < 2; ++i) {
            int c = tid + i * 256;
            int r = c >> 2, c8 = (c & 3) * 8;
            i32x4 v = *(const i32x4*)(A + (size_t)(m0 + r) * lda + k0 + c8);
            *(i32x4*)&As[r * 40 + c8] = v;
        }
#pragma unroll
        for (int i = 0; i < 2; ++i) {
            int c = tid + i * 256;
            int r = c >> 2, c8 = (c & 3) * 8;
            i32x4 v = {0, 0, 0, 0};
            if (n0 + r < N) v = *(const i32x4*)(B + (size_t)(n0 + r) * ldb + k0 + c8);
            *(i32x4*)&Bs[r * 40 + c8] = v;
        }
        __syncthreads();
        bf16x8 af[4], bfr[4];
#pragma unroll
        for (int i = 0; i < 4; ++i) af[i]  = *(const bf16x8*)&As[(wr + i * 16 + fr) * 40 + fk];
#pragma unroll
        for (int j = 0; j < 4; ++j) bfr[j] = *(const bf16x8*)&Bs[(wc + j * 16 + fr) * 40 + fk];
#pragma unroll
        for (int i = 0; i < 4; ++i)
#pragma unroll
            for (int j = 0; j < 4; ++j)
                acc[i][j] = __builtin_amdgcn_mfma_f32_16x16x32_bf16(af[i], bfr[j], acc[i][j], 0, 0, 0);
        __syncthreads();
    }
    const int er = (lane >> 4) * 4;
    if (EPI == 3) {
        unsigned short* xiT = (unsigned short*)C;
        unsigned short* zT  = (unsigned short*)C2;
#pragma unroll
        for (int i = 0; i < 4; ++i)
#pragma unroll
            for (int j = 0; j < 4; ++j) {
                int row0 = m0 + wr + i * 16 + er;
                int col = n0 + wc + j * 16 + fr;
                unsigned short* dst = (col < D_INNER)
                    ? xiT + (size_t)col * NTOK + row0
                    : zT + (size_t)(col - D_INNER) * NTOK + row0;
                unsigned short o[4];
#pragma unroll
                for (int r = 0; r < 4; ++r) o[r] = f2b(acc[i][j][r]);
                *(unsigned long long*)dst = *(unsigned long long*)o;
            }
    } else if (EPI == 1) {
        const unsigned short* uT = (const unsigned short*)res;   // u_T bf16, [d][token]
        unsigned int* ddu = (unsigned int*)C;
        unsigned short* uDb = (unsigned short*)C2;
#pragma unroll
        for (int i = 0; i < 4; ++i)
#pragma unroll
            for (int j = 0; j < 4; ++j) {
                int row0 = m0 + wr + i * 16 + er;
                int col = n0 + wc + j * 16 + fr;
                float bb = bias[col];
                float Dv = aux[col];
                u16x4 uu = *(const u16x4*)(uT + (size_t)col * NTOK + row0);
                i32x4 pk;
                unsigned short ud[4];
#pragma unroll
                for (int r = 0; r < 4; ++r) {
                    float t = acc[i][j][r] + bb;
                    float v = fmaxf(t, 0.f) + log1pf(expf(-fabsf(t)));   // softplus
                    float uf = b2f(uu[r]);
                    pk[r] = (int)(((unsigned)f2b(v)) | (((unsigned)f2b(v * uf)) << 16));
                    ud[r] = f2b(uf * Dv);
                }
                *(i32x4*)(ddu + (size_t)col * ldc + row0) = pk;
                *(unsigned long long*)(uDb + (size_t)col * ldc + row0) = *(unsigned long long*)ud;
            }
    } else {
        float* Cs = (float*)C + (size_t)blockIdx.z * M * ldc;
#pragma unroll
        for (int i = 0; i < 4; ++i)
#pragma unroll
            for (int j = 0; j < 4; ++j) {
                int col = n0 + wc + j * 16 + fr;
                if (col < N) {
#pragma unroll
                    for (int r = 0; r < 4; ++r) {
                        int row = m0 + wr + i * 16 + er + r;
                        Cs[(size_t)row * ldc + col] = acc[i][j][r];
                    }
                }
            }
    }
}

// ---------------- out_proj split-K combine + residual ----------------
__global__ void combine_residual(const float* __restrict__ part, const float* __restrict__ x,
                                 float* __restrict__ out) {
    int i = blockIdx.x * 256 + threadIdx.x;          // f32x4 index over NTOK*DIMX/4
    f32x4 s = *(const f32x4*)(x + (size_t)i * 4);
#pragma unroll
    for (int z = 0; z < 4; ++z)
        s += *(const f32x4*)(part + (size_t)z * NTOK * DIMX + (size_t)i * 4);
    *(f32x4*)(out + (size_t)i * 4) = s;
}

// ---------------- Depthwise causal conv + SiLU on transposed bf16: u_T[d][t] ----------------
__global__ __launch_bounds__(256) void conv_silu_t(const unsigned short* __restrict__ xiT,
                                                   const float* __restrict__ cw,
                                                   const float* __restrict__ cb,
                                                   unsigned short* __restrict__ u_T) {
    int idx = blockIdx.x * 256 + threadIdx.x;
    int g = idx & (NTOK / 16 - 1);                   // token group (128 per channel)
    int d = idx >> 7;
    int t0 = g * 16;
    const unsigned short* src = xiT + (size_t)d * NTOK + t0;
    bf16x8 v0 = *(const bf16x8*)(src);
    bf16x8 v1 = *(const bf16x8*)(src + 8);
    float xv[19];
    if (t0 & (L_SEQ - 1)) {
        xv[0] = b2f(src[-3]); xv[1] = b2f(src[-2]); xv[2] = b2f(src[-1]);
    } else {
        xv[0] = 0.f; xv[1] = 0.f; xv[2] = 0.f;
    }
#pragma unroll
    for (int i = 0; i < 8; ++i) xv[3 + i] = b2f((unsigned short)v0[i]);
#pragma unroll
    for (int i = 0; i < 8; ++i) xv[11 + i] = b2f((unsigned short)v1[i]);
    const float w0 = cw[d * 4 + 0], w1 = cw[d * 4 + 1], w2 = cw[d * 4 + 2], w3 = cw[d * 4 + 3];
    const float bias = cb[d];
    unsigned short o[16];
#pragma unroll
    for (int i = 0; i < 16; ++i) {
        float a = bias + w0 * xv[i] + w1 * xv[i + 1] + w2 * xv[i + 2] + w3 * xv[i + 3];
        o[i] = f2b(a / (1.f + __expf(-a)));
    }
    unsigned short* dst = u_T + (size_t)d * NTOK + t0;
    *(bf16x8*)(dst)     = *(bf16x8*)(o);
    *(bf16x8*)(dst + 8) = *(bf16x8*)(o + 8);
}

// ---------------- x_proj split-K combine ----------------
__global__ void xproj_combine(const float* __restrict__ xp, unsigned short* __restrict__ xdbl_b,
                              float* __restrict__ B_T, float* __restrict__ C_T) {
    int row = blockIdx.x;
    int col = threadIdx.x;
    if (col >= 96) return;
    float s = 0.f;
#pragma unroll
    for (int p = 0; p < 8; ++p) s += xp[(size_t)p * NTOK * 96 + (size_t)row * 96 + col];
    if (col < 64) xdbl_b[row * 64 + col] = f2b(s);
    else if (col < 80) B_T[(size_t)(col - 64) * NTOK + row] = s;
    else C_T[(size_t)(col - 80) * NTOK + row] = s;
}

// ================= Chunked selective scan (pinned 3-deep prefetch) =================

struct G1 { i32x4 p0, p1; f32x4 b0, b1; };

__device__ __forceinline__ void g1_load(G1& G, const unsigned int* pp, const float* pb, int g8) {
    G.p0 = *(const i32x4*)(pp + g8); G.p1 = *(const i32x4*)(pp + g8 + 4);
    G.b0 = *(const f32x4*)(pb + g8); G.b1 = *(const f32x4*)(pb + g8 + 4);
}
__device__ __forceinline__ void g1_proc(const G1& G, float& h, float& Pr, float A2) {
    float e[8], g[8];
#pragma unroll
    for (int q = 0; q < 8; ++q) {                       // independent of h: batch first
        unsigned int v = (unsigned int)((q < 4) ? G.p0[q] : G.p1[q - 4]);
        float bq = (q < 4) ? G.b0[q] : G.b1[q - 4];
        e[q] = exp2f(lo2f(v) * A2);
        g[q] = hi2f(v) * bq;
    }
#pragma unroll
    for (int q = 0; q < 8; ++q) h = e[q] * h + g[q];    // pure fma chain
    float ee = ((e[0] * e[1]) * (e[2] * e[3])) * ((e[4] * e[5]) * (e[6] * e[7]));
    Pr *= ee;
}

__global__ __launch_bounds__(256) void scan_pass1(
    const unsigned int* __restrict__ ddu, const float* __restrict__ B_T,
    const float* __restrict__ A_log, float* __restrict__ hl, float* __restrict__ Pc) {
    const int tid = threadIdx.x, lane = tid & 63;
    const int s = lane & 15;
    const int chunk = blockIdx.x & (NC - 1), grp = blockIdx.x >> 4;
    const int gchan = grp * 16 + (tid >> 6) * 4 + (lane >> 4);
    const int b = gchan >> 11, d = gchan & (D_INNER - 1);
    const float A2 = -__expf(A_log[d * D_STATE + s]) * LOG2E;
    const int tb = b * L_SEQ + chunk * LC;
    const unsigned int* pp = ddu + (size_t)d * NTOK + tb;
    const float* pb = B_T + (size_t)s * NTOK + tb;
    float h = 0.f, Pr = 1.f;
    G1 ga, gb, gc;
    g1_load(ga, pp, pb, 0);
    g1_load(gb, pp, pb, 8);
    g1_load(gc, pp, pb, 16);
    __builtin_amdgcn_sched_barrier(0);
    g1_proc(ga, h, Pr, A2); g1_load(ga, pp, pb, 24); __builtin_amdgcn_sched_barrier(0);
    g1_proc(gb, h, Pr, A2); g1_load(gb, pp, pb, 32); __builtin_amdgcn_sched_barrier(0);
    g1_proc(gc, h, Pr, A2); g1_load(gc, pp, pb, 40); __builtin_amdgcn_sched_barrier(0);
    g1_proc(ga, h, Pr, A2); g1_load(ga, pp, pb, 48); __builtin_amdgcn_sched_barrier(0);
    g1_proc(gb, h, Pr, A2); g1_load(gb, pp, pb, 56); __builtin_amdgcn_sched_barrier(0);
    g1_proc(gc, h, Pr, A2);
    g1_proc(ga, h, Pr, A2);
    g1_proc(gb, h, Pr, A2);
    int o = chunk * NLANE + gchan * D_STATE + s;
    hl[o] = h;
    Pc[o] = Pr;
}

__global__ __launch_bounds__(256) void scan_pass2(const float* __restrict__ hl,
                                                  const float* __restrict__ Pc,
                                                  float* __restrict__ hi) {
    int gid = blockIdx.x * 256 + threadIdx.x;
    float h = 0.f;
    hi[gid] = 0.f;
#pragma unroll
    for (int c = 1; c < NC; ++c) {
        h = hl[(c - 1) * NLANE + gid] + Pc[(c - 1) * NLANE + gid] * h;
        hi[c * NLANE + gid] = h;
    }
}

struct G3 { i32x4 p0, p1; f32x4 b0, b1, c0, c1; bf16x8 ud, z; };

__device__ __forceinline__ void g3_load(G3& G, const unsigned int* pp,
                                        const float* pb, const float* pc,
                                        const unsigned short* puD, const unsigned short* pz,
                                        int g8) {
    G.p0 = *(const i32x4*)(pp + g8); G.p1 = *(const i32x4*)(pp + g8 + 4);
    G.b0 = *(const f32x4*)(pb + g8); G.b1 = *(const f32x4*)(pb + g8 + 4);
    G.c0 = *(const f32x4*)(pc + g8); G.c1 = *(const f32x4*)(pc + g8 + 4);
    G.ud = *(const bf16x8*)(puD + g8);
    G.z  = *(const bf16x8*)(pz + g8);
}

// Batched e/g, pure fma h-chain, reduce-scatter, fused gate + transposed store.
__device__ __forceinline__ void g3_proc(const G3& G, float& h, float A2, int s,
                                        unsigned short* pyT, int g8) {
    float e[8], g[8];
#pragma unroll
    for (int q = 0; q < 8; ++q) {
        unsigned int v = (unsigned int)((q < 4) ? G.p0[q] : G.p1[q - 4]);
        float bq = (q < 4) ? G.b0[q] : G.b1[q - 4];
        e[q] = exp2f(lo2f(v) * A2);
        g[q] = hi2f(v) * bq;
    }
    float y[8];
#pragma unroll
    for (int q = 0; q < 8; ++q) {
        h = e[q] * h + g[q];
        float cq = (q < 4) ? G.c0[q] : G.c1[q - 4];
        y[q] = h * cq;
    }
    const bool b4 = (s & 4) != 0, b2_ = (s & 2) != 0, b1 = (s & 1) != 0;
#pragma unroll
    for (int i = 0; i < 4; ++i) {
        float give = b4 ? y[i] : y[i + 4];
        float keep = b4 ? y[i + 4] : y[i];
        y[i] = keep + __shfl_xor(give, 4);
    }
#pragma unroll
    for (int i = 0; i < 2; ++i) {
        float give = b2_ ? y[i] : y[i + 2];
        float keep = b2_ ? y[i + 2] : y[i];
        y[i] = keep + __shfl_xor(give, 2);
    }
    {
        float give = b1 ? y[0] : y[1];
        float keep = b1 ? y[1] : y[0];
        y[0] = keep + __shfl_xor(give, 1);
    }
    y[0] += __shfl_xor(y[0], 8);
    if (!(s & 8)) {
        int q = s & 7;
        float zz = b2f((unsigned short)G.z[q]);
        float yy = y[0] + b2f((unsigned short)G.ud[q]);
        pyT[g8 + q] = f2b(yy * (zz / (1.f + __expf(-zz))));
    }
}

__global__ __launch_bounds__(256) void scan_pass3(
    const unsigned int* __restrict__ ddu, const float* __restrict__ B_T,
    const float* __restrict__ C_T, const unsigned short* __restrict__ uD_b,
    const unsigned short* __restrict__ z_b, const float* __restrict__ A_log,
    const float* __restrict__ hi, unsigned short* __restrict__ y_T) {
    const int tid = threadIdx.x, lane = tid & 63;
    const int s = lane & 15;
    const int chunk = blockIdx.x & (NC - 1), grp = blockIdx.x >> 4;
    const int gchan = grp * 16 + (tid >> 6) * 4 + (lane >> 4);
    const int b = gchan >> 11, d = gchan & (D_INNER - 1);
    const float A2 = -__expf(A_log[d * D_STATE + s]) * LOG2E;
    const int tb = b * L_SEQ + chunk * LC;
    const unsigned int* pp = ddu + (size_t)d * NTOK + tb;
    const float* pb = B_T + (size_t)s * NTOK + tb;
    const float* pc = C_T + (size_t)s * NTOK + tb;
    const unsigned short* puD = uD_b + (size_t)d * NTOK + tb;
    const unsigned short* pz = z_b + (size_t)d * NTOK + tb;
    unsigned short* pyT = y_T + (size_t)d * NTOK + tb;
    float h = hi[chunk * NLANE + gchan * D_STATE + s];
    G3 ga, gb, gc;
    g3_load(ga, pp, pb, pc, puD, pz, 0);
    g3_load(gb, pp, pb, pc, puD, pz, 8);
    g3_load(gc, pp, pb, pc, puD, pz, 16);
    __builtin_amdgcn_sched_barrier(0);
    g3_proc(ga, h, A2, s, pyT, 0);  g3_load(ga, pp, pb, pc, puD, pz, 24); __builtin_amdgcn_sched_barrier(0);
    g3_proc(gb, h, A2, s, pyT, 8);  g3_load(gb, pp, pb, pc, puD, pz, 32); __builtin_amdgcn_sched_barrier(0);
    g3_proc(gc, h, A2, s, pyT, 16); g3_load(gc, pp, pb, pc, puD, pz, 40); __builtin_amdgcn_sched_barrier(0);
    g3_proc(ga, h, A2, s, pyT, 24); g3_load(ga, pp, pb, pc, puD, pz, 48); __builtin_amdgcn_sched_barrier(0);
    g3_proc(gb, h, A2, s, pyT, 32); g3_load(gb, pp, pb, pc, puD, pz, 56); __builtin_amdgcn_sched_barrier(0);
    g3_proc(gc, h, A2, s, pyT, 40);
    g3_proc(ga, h, A2, s, pyT, 48);
    g3_proc(gb, h, A2, s, pyT, 56);
}

extern "C" void kernel_launch(void* const* d_in, const int* in_sizes, int n_in,
                              void* d_out, int out_size, void* d_ws, size_t ws_size,
                              hipStream_t stream) {
    const float* x          = (const float*)d_in[0];
    const float* norm_w     = (const float*)d_in[1];
    const float* in_proj_w  = (const float*)d_in[2];
    const float* conv_w     = (const float*)d_in[3];
    const float* conv_b     = (const float*)d_in[4];
    const float* x_proj_w   = (const float*)d_in[5];
    const float* dt_proj_w  = (const float*)d_in[6];
    const float* dt_proj_b  = (const float*)d_in[7];
    const float* A_log      = (const float*)d_in[8];
    const float* D_param    = (const float*)d_in[9];
    const float* out_proj_w = (const float*)d_in[10];
    float* out = (float*)d_out;

    char* p = (char*)d_ws;
    unsigned short* xi_T = (unsigned short*)p; p += (size_t)D_INNER * NTOK * 2;   // 8.39 MB
    unsigned short* z_b  = (unsigned short*)p; p += (size_t)D_INNER * NTOK * 2;   // 8.39 MB
    unsigned int*   ddu  = (unsigned int*)p;   p += (size_t)D_INNER * NTOK * 4;   // 16.78 MB
    unsigned short* u_T  = (unsigned short*)p; p += (size_t)D_INNER * NTOK * 2;   // 8.39 MB
    unsigned short* uD_b = (unsigned short*)p; p += (size_t)D_INNER * NTOK * 2;   // 8.39 MB
    unsigned short* y_T  = (unsigned short*)p; p += (size_t)D_INNER * NTOK * 2;   // 8.39 MB
    unsigned short* xdbl_b = (unsigned short*)p; p += (size_t)NTOK * 64 * 2;      // 0.26 MB
    float* B_T = (float*)p;  p += (size_t)D_STATE * NTOK * 4;                     // 0.13 MB
    float* C_T = (float*)p;  p += (size_t)D_STATE * NTOK * 4;                     // 0.13 MB
    unsigned short* xn_b = (unsigned short*)p; p += (size_t)NTOK * DIMX * 2;      // 4.19 MB
    unsigned short* w_in_b  = (unsigned short*)p; p += (size_t)2 * D_INNER * DIMX * 2;  // 8.39 MB
    unsigned short* w_x_b   = (unsigned short*)p; p += (size_t)96 * D_INNER * 2;
    unsigned short* w_dt_b  = (unsigned short*)p; p += (size_t)D_INNER * DT_RANK * 2;
    unsigned short* w_out_b = (unsigned short*)p; p += (size_t)DIMX * D_INNER * 2;

    // overlays (disjoint lifetimes):
    float* xp_part = (float*)y_T;              // 6.29 MB (y_T written only by pass3)
    float* hl = (float*)w_in_b;                // 4.19 MB (w_in dead after in_proj; pass1+)
    float* Pc = hl + NC * NLANE;               // 4.19 MB
    float* hi = (float*)xn_b;                  // 4.19 MB (xn dead after in_proj; pass2+)
    unsigned short* u_row = (unsigned short*)w_in_b;  // 8.39 MB (post-conv .. x_proj, before hl/Pc)
    float* out_part = (float*)ddu;             // 33.5 MB = ddu+u_T+uD_b (all dead after pass3)

    // 0. weight conversions f32 -> bf16
    f2b_kernel<<<(2 * D_INNER * DIMX / 4 + 255) / 256, 256, 0, stream>>>(in_proj_w, w_in_b, 2 * D_INNER * DIMX / 4);
    f2b_kernel<<<(96 * D_INNER / 4 + 255) / 256, 256, 0, stream>>>(x_proj_w, w_x_b, 96 * D_INNER / 4);
    f2b_kernel<<<(D_INNER * DT_RANK / 4 + 255) / 256, 256, 0, stream>>>(dt_proj_w, w_dt_b, D_INNER * DT_RANK / 4);
    f2b_kernel<<<(DIMX * D_INNER / 4 + 255) / 256, 256, 0, stream>>>(out_proj_w, w_out_b, DIMX * D_INNER / 4);

    // 1. RMSNorm -> bf16
    rmsnorm_kernel<<<NTOK, 256, 0, stream>>>(x, norm_w, xn_b);
    // 2. in_proj: xi_T bf16 [d][t] + z_b bf16 [d][t]
    gemm_mfma<3><<<dim3(32, 16), 256, 0, stream>>>(xn_b, w_in_b, xi_T, z_b,
        NTOK, 2 * D_INNER, DIMX, DIMX, DIMX, NTOK, nullptr, nullptr, nullptr);
    // 3. conv + SiLU -> u_T bf16 [d][t]
    conv_silu_t<<<D_INNER * (NTOK / 16) / 256, 256, 0, stream>>>(xi_T, conv_w, conv_b, u_T);
    // 3b. transpose u_T -> u_row [t][d]  (w_in_b dead now)
    transpose_bf16<<<dim3(NTOK / 64, D_INNER / 64), 256, 0, stream>>>(u_T, u_row, D_INNER, NTOK);
    // 4. x_proj split-K=8 partials + combine
    gemm_mfma<0><<<dim3(1, 16, 8), 256, 0, stream>>>(u_row, w_x_b, xp_part, nullptr,
        NTOK, 96, D_INNER, D_INNER, D_INNER, 96, nullptr, nullptr, nullptr);
    xproj_combine<<<NTOK, 128, 0, stream>>>(xp_part, xdbl_b, B_T, C_T);
    // 5. dt_proj: ddu (packed bf16 delta,du) + uD_b (u*D)  [all transposed]
    gemm_mfma<1><<<dim3(16, 16), 256, 0, stream>>>(xdbl_b, w_dt_b, ddu, uD_b,
        NTOK, D_INNER, DT_RANK, 64, DT_RANK, NTOK, dt_proj_b, (const float*)u_T, D_param);
    // 6. chunked selective scan (gate fused into pass 3, transposed y)
    scan_pass1<<<4096, 256, 0, stream>>>(ddu, B_T, A_log, hl, Pc);
    scan_pass2<<<NLANE / 256, 256, 0, stream>>>(hl, Pc, hi);
    scan_pass3<<<4096, 256, 0, stream>>>(ddu, B_T, C_T, uD_b, z_b, A_log, hi, y_T);
    // 6b. transpose y_T -> y_row [t][d]  (xi_T dead after conv)
    transpose_bf16<<<dim3(NTOK / 64, D_INNER / 64), 256, 0, stream>>>(y_T, xi_T, D_INNER, NTOK);
    // 7. out_proj split-K=4 -> partials (ddu/u_T/uD_b region dead after pass3)
    gemm_mfma<0><<<dim3(8, 16, 4), 256, 0, stream>>>(xi_T, w_out_b, out_part, nullptr,
        NTOK, DIMX, D_INNER, D_INNER, D_INNER, DIMX, nullptr, nullptr, nullptr);
    // 8. combine partials + residual -> out
    combine_residual<<<NTOK * DIMX / 4 / 256, 256, 0, stream>>>(out_part, x, out);
}

// Round 12
// 258.783 us; speedup vs baseline: 1.0273x; 1.0273x over previous
//
#include <hip/hip_runtime.h>
#include <math.h>

#define DIMX 1024
#define D_STATE 16
#define D_INNER 2048
#define DT_RANK 64
#define B_SZ 2
#define L_SEQ 1024
#define NTOK (B_SZ * L_SEQ)
#define EPSR 1e-5f
#define NC 16          // chunks over sequence
#define LC 64          // steps per chunk
#define NCH (B_SZ * D_INNER)            // 4096 channels
#define NLANE (NCH * D_STATE)           // 65536 (chan,state) pairs
#define LOG2E 1.44269504f

typedef __attribute__((ext_vector_type(8))) short bf16x8;
typedef __attribute__((ext_vector_type(4))) int   i32x4;
typedef __attribute__((ext_vector_type(4))) float f32x4;
typedef __attribute__((ext_vector_type(4))) unsigned short u16x4;

__device__ __forceinline__ unsigned short f2b(float f) {
    unsigned int u = __builtin_bit_cast(unsigned int, f);
    u += 0x7fffu + ((u >> 16) & 1u);          // RNE
    return (unsigned short)(u >> 16);
}
__device__ __forceinline__ float b2f(unsigned short h) {
    unsigned int u = ((unsigned int)h) << 16;
    return __builtin_bit_cast(float, u);
}
__device__ __forceinline__ float lo2f(unsigned int v) {       // low bf16 -> f32
    return __builtin_bit_cast(float, v << 16);
}
__device__ __forceinline__ float hi2f(unsigned int v) {       // high bf16 -> f32
    return __builtin_bit_cast(float, v & 0xffff0000u);
}

// ---------------- all-weights f32 -> bf16 conversion (one kernel) ----------------
#define N1C (2 * D_INNER * DIMX / 4)
#define N2C (96 * D_INNER / 4)
#define N3C (D_INNER * DT_RANK / 4)
#define N4C (DIMX * D_INNER / 4)
__global__ void f2b_all(const float* __restrict__ w_in, const float* __restrict__ w_x,
                        const float* __restrict__ w_dt, const float* __restrict__ w_out,
                        unsigned short* __restrict__ o_in, unsigned short* __restrict__ o_x,
                        unsigned short* __restrict__ o_dt, unsigned short* __restrict__ o_out) {
    int i = blockIdx.x * 256 + threadIdx.x;
    const float* src; unsigned short* dst; int j;
    if (i < N1C)                       { src = w_in;  dst = o_in;  j = i; }
    else if (i < N1C + N2C)            { src = w_x;   dst = o_x;   j = i - N1C; }
    else if (i < N1C + N2C + N3C)      { src = w_dt;  dst = o_dt;  j = i - N1C - N2C; }
    else if (i < N1C + N2C + N3C + N4C){ src = w_out; dst = o_out; j = i - N1C - N2C - N3C; }
    else return;
    f32x4 v = *(const f32x4*)(src + (size_t)j * 4);
    unsigned short o[4];
#pragma unroll
    for (int k = 0; k < 4; ++k) o[k] = f2b(v[k]);
    *(unsigned long long*)(dst + (size_t)j * 4) = *(unsigned long long*)o;
}

// ---------------- RMSNorm ----------------
__global__ void rmsnorm_kernel(const float* __restrict__ x, const float* __restrict__ w,
                               unsigned short* __restrict__ xnb) {
    int row = blockIdx.x;
    const float* xr = x + (size_t)row * DIMX;
    unsigned short* outr = xnb + (size_t)row * DIMX;
    int t = threadIdx.x;
    float v[4];
    float ss = 0.f;
#pragma unroll
    for (int i = 0; i < 4; ++i) { v[i] = xr[t + i * 256]; ss += v[i] * v[i]; }
#pragma unroll
    for (int off = 32; off > 0; off >>= 1) ss += __shfl_down(ss, off);
    __shared__ float red[4];
    if ((t & 63) == 0) red[t >> 6] = ss;
    __syncthreads();
    float tot = red[0] + red[1] + red[2] + red[3];
    float scale = rsqrtf(tot * (1.f / DIMX) + EPSR);
#pragma unroll
    for (int i = 0; i < 4; ++i) outr[t + i * 256] = f2b(v[i] * scale * w[t + i * 256]);
}

// ---------------- bf16 64x64-tile transpose: dst[C][R] = src[R][C]^T ----------------
__global__ __launch_bounds__(256) void transpose_bf16(
    const unsigned short* __restrict__ src, unsigned short* __restrict__ dst,
    int R, int C) {
    __shared__ unsigned int xt[64 * 65];
    const int r0 = blockIdx.y * 64, c0 = blockIdx.x * 64;
    const int tid = threadIdx.x;
#pragma unroll
    for (int i = 0; i < 2; ++i) {
        int chunk = tid + i * 256;
        int r = chunk >> 3, cc = (chunk & 7) * 8;
        i32x4 v = *(const i32x4*)(src + (size_t)(r0 + r) * C + c0 + cc);
        const unsigned short* vs = (const unsigned short*)&v;
#pragma unroll
        for (int j = 0; j < 8; ++j) xt[(cc + j) * 65 + r] = vs[j];
    }
    __syncthreads();
#pragma unroll
    for (int i = 0; i < 2; ++i) {
        int chunk = tid + i * 256;
        int c = chunk >> 3, rr = (chunk & 7) * 8;
        unsigned short o[8];
#pragma unroll
        for (int j = 0; j < 8; ++j) o[j] = (unsigned short)xt[c * 65 + rr + j];
        *(i32x4*)(dst + (size_t)(c0 + c) * R + r0 + rr) = *(const i32x4*)o;
    }
}

// ---------------- FUSED depthwise causal conv + SiLU -> u_T [d][t] AND u_row [t][d] ----------------
// 64x64 (d x t) tile; xi_T staged to LDS with 3-token halo; output transposed via LDS.
__global__ __launch_bounds__(256) void conv_silu_tr(
    const unsigned short* __restrict__ xiT, const float* __restrict__ cw,
    const float* __restrict__ cb, unsigned short* __restrict__ u_T,
    unsigned short* __restrict__ u_row) {
    __shared__ unsigned int xs[67 * 65];     // f32 bits, [t_local 0..66][d 0..63], row=t0-3+j
    __shared__ unsigned int ob[64 * 65];     // u16 widened, [t_local][d]
    const int t0 = blockIdx.x * 64;
    const int d0 = blockIdx.y * 64;
    const int bstart = t0 & ~(L_SEQ - 1);
    const int tid = threadIdx.x;
    // load phase: 64 d-rows x 9 aligned 8-token chunks covering t0-8 .. t0+63
    for (int task = tid; task < 576; task += 256) {
        int d = task & 63, c = task >> 6;
        int tc = t0 - 8 + c * 8;                       // logical first token of chunk
        int tl = tc < 0 ? 0 : tc;                      // clamped (safe) load address
        i32x4 v = *(const i32x4*)(xiT + (size_t)(d0 + d) * NTOK + tl);
        const unsigned short* vs = (const unsigned short*)&v;
#pragma unroll
        for (int i = 0; i < 8; ++i) {
            int t = tc + i;
            int row = t - (t0 - 3);
            if (row >= 0 && row < 67) {
                float xv = (t >= bstart) ? b2f(vs[i]) : 0.f;
                xs[row * 65 + d] = __builtin_bit_cast(unsigned int, xv);
            }
        }
    }
    __syncthreads();
    // compute phase: lane = (dl, tr); 16 tokens per thread
    {
        const int dl = tid & 63, tr = tid >> 6;
        const int d = d0 + dl, lt0 = tr * 16;
        const float w0 = cw[d * 4 + 0], w1 = cw[d * 4 + 1], w2 = cw[d * 4 + 2], w3 = cw[d * 4 + 3];
        const float bias = cb[d];
        float x0 = __builtin_bit_cast(float, xs[(lt0 + 0) * 65 + dl]);
        float x1 = __builtin_bit_cast(float, xs[(lt0 + 1) * 65 + dl]);
        float x2 = __builtin_bit_cast(float, xs[(lt0 + 2) * 65 + dl]);
        unsigned short o[16];
#pragma unroll
        for (int i = 0; i < 16; ++i) {
            float x3 = __builtin_bit_cast(float, xs[(lt0 + 3 + i) * 65 + dl]);
            float a = bias + w0 * x0 + w1 * x1 + w2 * x2 + w3 * x3;
            unsigned short us = f2b(a / (1.f + __expf(-a)));
            o[i] = us;
            ob[(lt0 + i) * 65 + dl] = us;
            x0 = x1; x1 = x2; x2 = x3;
        }
        unsigned short* dst = u_T + (size_t)d * NTOK + t0 + lt0;
        *(bf16x8*)(dst)     = *(bf16x8*)(o);
        *(bf16x8*)(dst + 8) = *(bf16x8*)(o + 8);
    }
    __syncthreads();
    // output phase: transposed u_row [t][d]
#pragma unroll
    for (int it = 0; it < 2; ++it) {
        int k = tid + it * 256;
        int t = k >> 3, d8 = (k & 7) * 8;
        unsigned short o[8];
#pragma unroll
        for (int j = 0; j < 8; ++j) o[j] = (unsigned short)ob[t * 65 + d8 + j];
        *(i32x4*)(u_row + (size_t)(t0 + t) * D_INNER + d0 + d8) = *(const i32x4*)o;
    }
}

// ---------------- bf16 MFMA GEMM: C[M,N] = A[M,K] * B[N,K]^T (A,B bf16 row-major) ----------------
// EPI 0: row-major f32 partial store (split-K via blockIdx.z plane offset)
// EPI 1: dt_proj: delta = softplus(acc+bias[col]);
//        C (u32) <- pack(bf16(delta), bf16(delta*u)) [transposed]; C2 (bf16) <- u*aux[col]
// EPI 3: in_proj: col<2048 -> C bf16 transposed (xi_T), else C2 bf16 transposed (z_b)
template <int EPI>
__global__ __launch_bounds__(256) void gemm_mfma(
    const unsigned short* __restrict__ A, const unsigned short* __restrict__ B,
    void* __restrict__ C, void* __restrict__ C2,
    int M, int N, int K, int lda, int ldb, int ldc,
    const float* __restrict__ bias, const float* __restrict__ res,
    const float* __restrict__ aux) {
    __shared__ unsigned short As[128 * 40];
    __shared__ unsigned short Bs[128 * 40];
    const int tid = threadIdx.x;
    const int m0 = blockIdx.y * 128, n0 = blockIdx.x * 128;
    const int lane = tid & 63, wave = tid >> 6;
    const int wr = (wave >> 1) * 64, wc = (wave & 1) * 64;
    const int fr = lane & 15, fk = (lane >> 4) * 8;
    const int kspan = K / gridDim.z;
    const int kb = blockIdx.z * kspan;
    f32x4 acc[4][4] = {};
    for (int k0 = kb; k0 < kb + kspan; k0 += 32) {
#pragma unroll
        for (int i = 0; i < 2; ++i) {
            int c = tid + i * 256;
            int r = c >> 2, c8 = (c & 3) * 8;
            i32x4 v = *(const i32x4*)(A + (size_t)(m0 + r) * lda + k0 + c8);
            *(i32x4*)&As[r * 40 + c8] = v;
        }
#pragma unroll
        for (int i = 0; i < 2; ++i) {
            int c = tid + i * 256;
            int r = c >> 2, c8 = (c & 3) * 8;
            i32x4 v = {0, 0, 0, 0};
            if (n0 + r < N) v = *(const i32x4*)(B + (size_t)(n0 + r) * ldb + k0 + c8);
            *(i32x4*)&Bs[r * 40 + c8] = v;
        }
        __syncthreads();
        bf16x8 af[4], bfr[4];
#pragma unroll
        for (int i = 0; i < 4; ++i) af[i]  = *(const bf16x8*)&As[(wr + i * 16 + fr) * 40 + fk];
#pragma unroll
        for (int j = 0; j < 4; ++j) bfr[j] = *(const bf16x8*)&Bs[(wc + j * 16 + fr) * 40 + fk];
#pragma unroll
        for (int i = 0; i < 4; ++i)
#pragma unroll
            for (int j = 0; j < 4; ++j)
                acc[i][j] = __builtin_amdgcn_mfma_f32_16x16x32_bf16(af[i], bfr[j], acc[i][j], 0, 0, 0);
        __syncthreads();
    }
    const int er = (lane >> 4) * 4;
    if (EPI == 3) {
        unsigned short* xiT = (unsigned short*)C;
        unsigned short* zT  = (unsigned short*)C2;
#pragma unroll
        for (int i = 0; i < 4; ++i)
#pragma unroll
            for (int j = 0; j < 4; ++j) {
                int row0 = m0 + wr + i * 16 + er;
                int col = n0 + wc + j * 16 + fr;
                unsigned short* dst = (col < D_INNER)
                    ? xiT + (size_t)col * NTOK + row0
                    : zT + (size_t)(col - D_INNER) * NTOK + row0;
                unsigned short o[4];
#pragma unroll
                for (int r = 0; r < 4; ++r) o[r] = f2b(acc[i][j][r]);
                *(unsigned long long*)dst = *(unsigned long long*)o;
            }
    } else if (EPI == 1) {
        const unsigned short* uT = (const unsigned short*)res;   // u_T bf16, [d][token]
        unsigned int* ddu = (unsigned int*)C;
        unsigned short* uDb = (unsigned short*)C2;
#pragma unroll
        for (int i = 0; i < 4; ++i)
#pragma unroll
            for (int j = 0; j < 4; ++j) {
                int row0 = m0 + wr + i * 16 + er;
                int col = n0 + wc + j * 16 + fr;
                float bb = bias[col];
                float Dv = aux[col];
                u16x4 uu = *(const u16x4*)(uT + (size_t)col * NTOK + row0);
                i32x4 pk;
                unsigned short ud[4];
#pragma unroll
                for (int r = 0; r < 4; ++r) {
                    float t = acc[i][j][r] + bb;
                    float v = fmaxf(t, 0.f) + log1pf(expf(-fabsf(t)));   // softplus
                    float uf = b2f(uu[r]);
                    pk[r] = (int)(((unsigned)f2b(v)) | (((unsigned)f2b(v * uf)) << 16));
                    ud[r] = f2b(uf * Dv);
                }
                *(i32x4*)(ddu + (size_t)col * ldc + row0) = pk;
                *(unsigned long long*)(uDb + (size_t)col * ldc + row0) = *(unsigned long long*)ud;
            }
    } else {
        float* Cs = (float*)C + (size_t)blockIdx.z * M * ldc;
#pragma unroll
        for (int i = 0; i < 4; ++i)
#pragma unroll
            for (int j = 0; j < 4; ++j) {
                int col = n0 + wc + j * 16 + fr;
                if (col < N) {
#pragma unroll
                    for (int r = 0; r < 4; ++r) {
                        int row = m0 + wr + i * 16 + er + r;
                        Cs[(size_t)row * ldc + col] = acc[i][j][r];
                    }
                }
            }
    }
}

// ---------------- out_proj split-K combine + residual ----------------
__global__ void combine_residual(const float* __restrict__ part, const float* __restrict__ x,
                                 float* __restrict__ out) {
    int i = blockIdx.x * 256 + threadIdx.x;          // f32x4 index over NTOK*DIMX/4
    f32x4 s = *(const f32x4*)(x + (size_t)i * 4);
#pragma unroll
    for (int z = 0; z < 4; ++z)
        s += *(const f32x4*)(part + (size_t)z * NTOK * DIMX + (size_t)i * 4);
    *(f32x4*)(out + (size_t)i * 4) = s;
}

// ---------------- x_proj split-K combine ----------------
__global__ void xproj_combine(const float* __restrict__ xp, unsigned short* __restrict__ xdbl_b,
                              float* __restrict__ B_T, float* __restrict__ C_T) {
    int row = blockIdx.x;
    int col = threadIdx.x;
    if (col >= 96) return;
    float s = 0.f;
#pragma unroll
    for (int p = 0; p < 8; ++p) s += xp[(size_t)p * NTOK * 96 + (size_t)row * 96 + col];
    if (col < 64) xdbl_b[row * 64 + col] = f2b(s);
    else if (col < 80) B_T[(size_t)(col - 64) * NTOK + row] = s;
    else C_T[(size_t)(col - 80) * NTOK + row] = s;
}

// ================= Chunked selective scan (R10 best config) =================

struct G1 { i32x4 p0, p1; f32x4 b0, b1; };

__device__ __forceinline__ void g1_load(G1& G, const unsigned int* pp, const float* pb, int g8) {
    G.p0 = *(const i32x4*)(pp + g8); G.p1 = *(const i32x4*)(pp + g8 + 4);
    G.b0 = *(const f32x4*)(pb + g8); G.b1 = *(const f32x4*)(pb + g8 + 4);
}
__device__ __forceinline__ void g1_proc(const G1& G, float& h, float& Pr, float A2) {
    float e[8], g[8];
#pragma unroll
    for (int q = 0; q < 8; ++q) {                       // independent of h: batch first
        unsigned int v = (unsigned int)((q < 4) ? G.p0[q] : G.p1[q - 4]);
        float bq = (q < 4) ? G.b0[q] : G.b1[q - 4];
        e[q] = exp2f(lo2f(v) * A2);
        g[q] = hi2f(v) * bq;
    }
#pragma unroll
    for (int q = 0; q < 8; ++q) h = e[q] * h + g[q];    // pure fma chain
    float ee = ((e[0] * e[1]) * (e[2] * e[3])) * ((e[4] * e[5]) * (e[6] * e[7]));
    Pr *= ee;
}

__global__ __launch_bounds__(256) void scan_pass1(
    const unsigned int* __restrict__ ddu, const float* __restrict__ B_T,
    const float* __restrict__ A_log, float* __restrict__ hl, float* __restrict__ Pc) {
    const int tid = threadIdx.x, lane = tid & 63;
    const int s = lane & 15;
    const int chunk = blockIdx.x & (NC - 1), grp = blockIdx.x >> 4;
    const int gchan = grp * 16 + (tid >> 6) * 4 + (lane >> 4);
    const int b = gchan >> 11, d = gchan & (D_INNER - 1);
    const float A2 = -__expf(A_log[d * D_STATE + s]) * LOG2E;
    const int tb = b * L_SEQ + chunk * LC;
    const unsigned int* pp = ddu + (size_t)d * NTOK + tb;
    const float* pb = B_T + (size_t)s * NTOK + tb;
    float h = 0.f, Pr = 1.f;
    G1 ga, gb, gc;
    g1_load(ga, pp, pb, 0);
    g1_load(gb, pp, pb, 8);
    g1_load(gc, pp, pb, 16);
    g1_proc(ga, h, Pr, A2); g1_load(ga, pp, pb, 24);
    g1_proc(gb, h, Pr, A2); g1_load(gb, pp, pb, 32);
    g1_proc(gc, h, Pr, A2); g1_load(gc, pp, pb, 40);
    g1_proc(ga, h, Pr, A2); g1_load(ga, pp, pb, 48);
    g1_proc(gb, h, Pr, A2); g1_load(gb, pp, pb, 56);
    g1_proc(gc, h, Pr, A2);
    g1_proc(ga, h, Pr, A2);
    g1_proc(gb, h, Pr, A2);
    int o = chunk * NLANE + gchan * D_STATE + s;
    hl[o] = h;
    Pc[o] = Pr;
}

__global__ __launch_bounds__(256) void scan_pass2(const float* __restrict__ hl,
                                                  const float* __restrict__ Pc,
                                                  float* __restrict__ hi) {
    int gid = blockIdx.x * 256 + threadIdx.x;
    float h = 0.f;
    hi[gid] = 0.f;
#pragma unroll
    for (int c = 1; c < NC; ++c) {
        h = hl[(c - 1) * NLANE + gid] + Pc[(c - 1) * NLANE + gid] * h;
        hi[c * NLANE + gid] = h;
    }
}

struct G3 { i32x4 p0, p1; f32x4 b0, b1, c0, c1; };

__device__ __forceinline__ void g3_load(G3& G, const unsigned int* pp,
                                        const float* pb, const float* pc, int g8) {
    G.p0 = *(const i32x4*)(pp + g8); G.p1 = *(const i32x4*)(pp + g8 + 4);
    G.b0 = *(const f32x4*)(pb + g8); G.b1 = *(const f32x4*)(pb + g8 + 4);
    G.c0 = *(const f32x4*)(pc + g8); G.c1 = *(const f32x4*)(pc + g8 + 4);
}

// Batched e/g, pure fma h-chain, reduce-scatter, fused gate + transposed store.
__device__ __forceinline__ void g3_proc(const G3& G, float& h, float A2, int s,
                                        const unsigned short* puD, const unsigned short* pz,
                                        unsigned short* pyT, int g8) {
    float e[8], g[8];
#pragma unroll
    for (int q = 0; q < 8; ++q) {
        unsigned int v = (unsigned int)((q < 4) ? G.p0[q] : G.p1[q - 4]);
        float bq = (q < 4) ? G.b0[q] : G.b1[q - 4];
        e[q] = exp2f(lo2f(v) * A2);
        g[q] = hi2f(v) * bq;
    }
    float y[8];
#pragma unroll
    for (int q = 0; q < 8; ++q) {
        h = e[q] * h + g[q];
        float cq = (q < 4) ? G.c0[q] : G.c1[q - 4];
        y[q] = h * cq;
    }
    const bool b4 = (s & 4) != 0, b2_ = (s & 2) != 0, b1 = (s & 1) != 0;
#pragma unroll
    for (int i = 0; i < 4; ++i) {
        float give = b4 ? y[i] : y[i + 4];
        float keep = b4 ? y[i + 4] : y[i];
        y[i] = keep + __shfl_xor(give, 4);
    }
#pragma unroll
    for (int i = 0; i < 2; ++i) {
        float give = b2_ ? y[i] : y[i + 2];
        float keep = b2_ ? y[i + 2] : y[i];
        y[i] = keep + __shfl_xor(give, 2);
    }
    {
        float give = b1 ? y[0] : y[1];
        float keep = b1 ? y[1] : y[0];
        y[0] = keep + __shfl_xor(give, 1);
    }
    y[0] += __shfl_xor(y[0], 8);
    if (!(s & 8)) {
        int q = s & 7;
        float zz = b2f(pz[g8 + q]);
        float yy = y[0] + b2f(puD[g8 + q]);
        pyT[g8 + q] = f2b(yy * (zz / (1.f + __expf(-zz))));
    }
}

__global__ __launch_bounds__(256) void scan_pass3(
    const unsigned int* __restrict__ ddu, const float* __restrict__ B_T,
    const float* __restrict__ C_T, const unsigned short* __restrict__ uD_b,
    const unsigned short* __restrict__ z_b, const float* __restrict__ A_log,
    const float* __restrict__ hi, unsigned short* __restrict__ y_T) {
    const int tid = threadIdx.x, lane = tid & 63;
    const int s = lane & 15;
    const int chunk = blockIdx.x & (NC - 1), grp = blockIdx.x >> 4;
    const int gchan = grp * 16 + (tid >> 6) * 4 + (lane >> 4);
    const int b = gchan >> 11, d = gchan & (D_INNER - 1);
    const float A2 = -__expf(A_log[d * D_STATE + s]) * LOG2E;
    const int tb = b * L_SEQ + chunk * LC;
    const unsigned int* pp = ddu + (size_t)d * NTOK + tb;
    const float* pb = B_T + (size_t)s * NTOK + tb;
    const float* pc = C_T + (size_t)s * NTOK + tb;
    const unsigned short* puD = uD_b + (size_t)d * NTOK + tb;
    const unsigned short* pz = z_b + (size_t)d * NTOK + tb;
    unsigned short* pyT = y_T + (size_t)d * NTOK + tb;
    float h = hi[chunk * NLANE + gchan * D_STATE + s];
    G3 ga, gb, gc;
    g3_load(ga, pp, pb, pc, 0);
    g3_load(gb, pp, pb, pc, 8);
    g3_load(gc, pp, pb, pc, 16);
    g3_proc(ga, h, A2, s, puD, pz, pyT, 0);  g3_load(ga, pp, pb, pc, 24);
    g3_proc(gb, h, A2, s, puD, pz, pyT, 8);  g3_load(gb, pp, pb, pc, 32);
    g3_proc(gc, h, A2, s, puD, pz, pyT, 16); g3_load(gc, pp, pb, pc, 40);
    g3_proc(ga, h, A2, s, puD, pz, pyT, 24); g3_load(ga, pp, pb, pc, 48);
    g3_proc(gb, h, A2, s, puD, pz, pyT, 32); g3_load(gb, pp, pb, pc, 56);
    g3_proc(gc, h, A2, s, puD, pz, pyT, 40);
    g3_proc(ga, h, A2, s, puD, pz, pyT, 48);
    g3_proc(gb, h, A2, s, puD, pz, pyT, 56);
}

extern "C" void kernel_launch(void* const* d_in, const int* in_sizes, int n_in,
                              void* d_out, int out_size, void* d_ws, size_t ws_size,
                              hipStream_t stream) {
    const float* x          = (const float*)d_in[0];
    const float* norm_w     = (const float*)d_in[1];
    const float* in_proj_w  = (const float*)d_in[2];
    const float* conv_w     = (const float*)d_in[3];
    const float* conv_b     = (const float*)d_in[4];
    const float* x_proj_w   = (const float*)d_in[5];
    const float* dt_proj_w  = (const float*)d_in[6];
    const float* dt_proj_b  = (const float*)d_in[7];
    const float* A_log      = (const float*)d_in[8];
    const float* D_param    = (const float*)d_in[9];
    const float* out_proj_w = (const float*)d_in[10];
    float* out = (float*)d_out;

    char* p = (char*)d_ws;
    unsigned short* xi_T = (unsigned short*)p; p += (size_t)D_INNER * NTOK * 2;   // 8.39 MB
    unsigned short* z_b  = (unsigned short*)p; p += (size_t)D_INNER * NTOK * 2;   // 8.39 MB
    unsigned int*   ddu  = (unsigned int*)p;   p += (size_t)D_INNER * NTOK * 4;   // 16.78 MB
    unsigned short* u_T  = (unsigned short*)p; p += (size_t)D_INNER * NTOK * 2;   // 8.39 MB
    unsigned short* uD_b = (unsigned short*)p; p += (size_t)D_INNER * NTOK * 2;   // 8.39 MB
    unsigned short* y_T  = (unsigned short*)p; p += (size_t)D_INNER * NTOK * 2;   // 8.39 MB
    unsigned short* xdbl_b = (unsigned short*)p; p += (size_t)NTOK * 64 * 2;      // 0.26 MB
    float* B_T = (float*)p;  p += (size_t)D_STATE * NTOK * 4;                     // 0.13 MB
    float* C_T = (float*)p;  p += (size_t)D_STATE * NTOK * 4;                     // 0.13 MB
    unsigned short* xn_b = (unsigned short*)p; p += (size_t)NTOK * DIMX * 2;      // 4.19 MB
    unsigned short* w_in_b  = (unsigned short*)p; p += (size_t)2 * D_INNER * DIMX * 2;  // 8.39 MB
    unsigned short* w_x_b   = (unsigned short*)p; p += (size_t)96 * D_INNER * 2;
    unsigned short* w_dt_b  = (unsigned short*)p; p += (size_t)D_INNER * DT_RANK * 2;
    unsigned short* w_out_b = (unsigned short*)p; p += (size_t)DIMX * D_INNER * 2;

    // overlays (disjoint lifetimes):
    float* xp_part = (float*)y_T;              // 6.29 MB (y_T written only by pass3)
    float* hl = (float*)w_in_b;                // 4.19 MB (w_in dead after in_proj; pass1+)
    float* Pc = hl + NC * NLANE;               // 4.19 MB
    float* hi = (float*)xn_b;                  // 4.19 MB (xn dead after in_proj; pass2+)
    unsigned short* u_row = (unsigned short*)w_in_b;  // 8.39 MB (post-conv .. x_proj, before hl/Pc)
    float* out_part = (float*)ddu;             // 33.5 MB = ddu+u_T+uD_b (all dead after pass3)

    // 0. all weight conversions f32 -> bf16 (one kernel)
    f2b_all<<<(N1C + N2C + N3C + N4C + 255) / 256, 256, 0, stream>>>(
        in_proj_w, x_proj_w, dt_proj_w, out_proj_w, w_in_b, w_x_b, w_dt_b, w_out_b);

    // 1. RMSNorm -> bf16
    rmsnorm_kernel<<<NTOK, 256, 0, stream>>>(x, norm_w, xn_b);
    // 2. in_proj: xi_T bf16 [d][t] + z_b bf16 [d][t]
    gemm_mfma<3><<<dim3(32, 16), 256, 0, stream>>>(xn_b, w_in_b, xi_T, z_b,
        NTOK, 2 * D_INNER, DIMX, DIMX, DIMX, NTOK, nullptr, nullptr, nullptr);
    // 3. FUSED conv + SiLU -> u_T [d][t] AND u_row [t][d]  (w_in_b dead after in_proj)
    conv_silu_tr<<<dim3(NTOK / 64, D_INNER / 64), 256, 0, stream>>>(
        xi_T, conv_w, conv_b, u_T, u_row);
    // 4. x_proj split-K=8 partials + combine
    gemm_mfma<0><<<dim3(1, 16, 8), 256, 0, stream>>>(u_row, w_x_b, xp_part, nullptr,
        NTOK, 96, D_INNER, D_INNER, D_INNER, 96, nullptr, nullptr, nullptr);
    xproj_combine<<<NTOK, 128, 0, stream>>>(xp_part, xdbl_b, B_T, C_T);
    // 5. dt_proj: ddu (packed bf16 delta,du) + uD_b (u*D)  [all transposed]
    gemm_mfma<1><<<dim3(16, 16), 256, 0, stream>>>(xdbl_b, w_dt_b, ddu, uD_b,
        NTOK, D_INNER, DT_RANK, 64, DT_RANK, NTOK, dt_proj_b, (const float*)u_T, D_param);
    // 6. chunked selective scan (gate fused into pass 3, transposed y)
    scan_pass1<<<4096, 256, 0, stream>>>(ddu, B_T, A_log, hl, Pc);
    scan_pass2<<<NLANE / 256, 256, 0, stream>>>(hl, Pc, hi);
    scan_pass3<<<4096, 256, 0, stream>>>(ddu, B_T, C_T, uD_b, z_b, A_log, hi, y_T);
    // 6b. transpose y_T -> y_row [t][d]  (xi_T dead after conv)
    transpose_bf16<<<dim3(NTOK / 64, D_INNER / 64), 256, 0, stream>>>(y_T, xi_T, D_INNER, NTOK);
    // 7. out_proj split-K=4 -> partials (ddu/u_T/uD_b region dead after pass3)
    gemm_mfma<0><<<dim3(8, 16, 4), 256, 0, stream>>>(xi_T, w_out_b, out_part, nullptr,
        NTOK, DIMX, D_INNER, D_INNER, D_INNER, DIMX, nullptr, nullptr, nullptr);
    // 8. combine partials + residual -> out
    combine_residual<<<NTOK * DIMX / 4 / 256, 256, 0, stream>>>(out_part, x, out);
}

// Round 13
// 240.286 us; speedup vs baseline: 1.1064x; 1.0770x over previous
//
#include <hip/hip_runtime.h>
#include <math.h>

#define DIMX 1024
#define D_STATE 16
#define D_INNER 2048
#define DT_RANK 64
#define B_SZ 2
#define L_SEQ 1024
#define NTOK (B_SZ * L_SEQ)
#define EPSR 1e-5f
#define NC 16          // chunks over sequence
#define LC 64          // steps per chunk
#define NCH (B_SZ * D_INNER)            // 4096 channels
#define NLANE (NCH * D_STATE)           // 65536 (chan,state) pairs
#define LOG2E 1.44269504f

typedef __attribute__((ext_vector_type(8))) short bf16x8;
typedef __attribute__((ext_vector_type(4))) int   i32x4;
typedef __attribute__((ext_vector_type(4))) float f32x4;
typedef __attribute__((ext_vector_type(4))) unsigned short u16x4;

__device__ __forceinline__ unsigned short f2b(float f) {
    unsigned int u = __builtin_bit_cast(unsigned int, f);
    u += 0x7fffu + ((u >> 16) & 1u);          // RNE
    return (unsigned short)(u >> 16);
}
__device__ __forceinline__ float b2f(unsigned short h) {
    unsigned int u = ((unsigned int)h) << 16;
    return __builtin_bit_cast(float, u);
}
__device__ __forceinline__ float lo2f(unsigned int v) {       // low bf16 -> f32
    return __builtin_bit_cast(float, v << 16);
}
__device__ __forceinline__ float hi2f(unsigned int v) {       // high bf16 -> f32
    return __builtin_bit_cast(float, v & 0xffff0000u);
}
// async global->LDS, 16B per lane, wave-uniform LDS base + lane*16
__device__ __forceinline__ void gload16(const void* g, void* l) {
    __builtin_amdgcn_global_load_lds(
        (const __attribute__((address_space(1))) unsigned int*)g,
        (__attribute__((address_space(3))) unsigned int*)l, 16, 0, 0);
}

// ---------------- all-weights f32 -> bf16 conversion (one kernel) ----------------
#define N1C (2 * D_INNER * DIMX / 4)
#define N2C (96 * D_INNER / 4)
#define N3C (D_INNER * DT_RANK / 4)
#define N4C (DIMX * D_INNER / 4)
__global__ void f2b_all(const float* __restrict__ w_in, const float* __restrict__ w_x,
                        const float* __restrict__ w_dt, const float* __restrict__ w_out,
                        unsigned short* __restrict__ o_in, unsigned short* __restrict__ o_x,
                        unsigned short* __restrict__ o_dt, unsigned short* __restrict__ o_out) {
    int i = blockIdx.x * 256 + threadIdx.x;
    const float* src; unsigned short* dst; int j;
    if (i < N1C)                       { src = w_in;  dst = o_in;  j = i; }
    else if (i < N1C + N2C)            { src = w_x;   dst = o_x;   j = i - N1C; }
    else if (i < N1C + N2C + N3C)      { src = w_dt;  dst = o_dt;  j = i - N1C - N2C; }
    else if (i < N1C + N2C + N3C + N4C){ src = w_out; dst = o_out; j = i - N1C - N2C - N3C; }
    else return;
    f32x4 v = *(const f32x4*)(src + (size_t)j * 4);
    unsigned short o[4];
#pragma unroll
    for (int k = 0; k < 4; ++k) o[k] = f2b(v[k]);
    *(unsigned long long*)(dst + (size_t)j * 4) = *(unsigned long long*)o;
}

// ---------------- RMSNorm ----------------
__global__ void rmsnorm_kernel(const float* __restrict__ x, const float* __restrict__ w,
                               unsigned short* __restrict__ xnb) {
    int row = blockIdx.x;
    const float* xr = x + (size_t)row * DIMX;
    unsigned short* outr = xnb + (size_t)row * DIMX;
    int t = threadIdx.x;
    float v[4];
    float ss = 0.f;
#pragma unroll
    for (int i = 0; i < 4; ++i) { v[i] = xr[t + i * 256]; ss += v[i] * v[i]; }
#pragma unroll
    for (int off = 32; off > 0; off >>= 1) ss += __shfl_down(ss, off);
    __shared__ float red[4];
    if ((t & 63) == 0) red[t >> 6] = ss;
    __syncthreads();
    float tot = red[0] + red[1] + red[2] + red[3];
    float scale = rsqrtf(tot * (1.f / DIMX) + EPSR);
#pragma unroll
    for (int i = 0; i < 4; ++i) outr[t + i * 256] = f2b(v[i] * scale * w[t + i * 256]);
}

// ---------------- bf16 64x64-tile transpose: dst[C][R] = src[R][C]^T ----------------
__global__ __launch_bounds__(256) void transpose_bf16(
    const unsigned short* __restrict__ src, unsigned short* __restrict__ dst,
    int R, int C) {
    __shared__ unsigned int xt[64 * 65];
    const int r0 = blockIdx.y * 64, c0 = blockIdx.x * 64;
    const int tid = threadIdx.x;
#pragma unroll
    for (int i = 0; i < 2; ++i) {
        int chunk = tid + i * 256;
        int r = chunk >> 3, cc = (chunk & 7) * 8;
        i32x4 v = *(const i32x4*)(src + (size_t)(r0 + r) * C + c0 + cc);
        const unsigned short* vs = (const unsigned short*)&v;
#pragma unroll
        for (int j = 0; j < 8; ++j) xt[(cc + j) * 65 + r] = vs[j];
    }
    __syncthreads();
#pragma unroll
    for (int i = 0; i < 2; ++i) {
        int chunk = tid + i * 256;
        int c = chunk >> 3, rr = (chunk & 7) * 8;
        unsigned short o[8];
#pragma unroll
        for (int j = 0; j < 8; ++j) o[j] = (unsigned short)xt[c * 65 + rr + j];
        *(i32x4*)(dst + (size_t)(c0 + c) * R + r0 + rr) = *(const i32x4*)o;
    }
}

// ---------------- FUSED depthwise causal conv + SiLU -> u_T [d][t] AND u_row [t][d] ----------------
__global__ __launch_bounds__(256) void conv_silu_tr(
    const unsigned short* __restrict__ xiT, const float* __restrict__ cw,
    const float* __restrict__ cb, unsigned short* __restrict__ u_T,
    unsigned short* __restrict__ u_row) {
    __shared__ unsigned int xs[67 * 65];
    __shared__ unsigned int ob[64 * 65];
    const int t0 = blockIdx.x * 64;
    const int d0 = blockIdx.y * 64;
    const int bstart = t0 & ~(L_SEQ - 1);
    const int tid = threadIdx.x;
    for (int task = tid; task < 576; task += 256) {
        int d = task & 63, c = task >> 6;
        int tc = t0 - 8 + c * 8;
        int tl = tc < 0 ? 0 : tc;
        i32x4 v = *(const i32x4*)(xiT + (size_t)(d0 + d) * NTOK + tl);
        const unsigned short* vs = (const unsigned short*)&v;
#pragma unroll
        for (int i = 0; i < 8; ++i) {
            int t = tc + i;
            int row = t - (t0 - 3);
            if (row >= 0 && row < 67) {
                float xv = (t >= bstart) ? b2f(vs[i]) : 0.f;
                xs[row * 65 + d] = __builtin_bit_cast(unsigned int, xv);
            }
        }
    }
    __syncthreads();
    {
        const int dl = tid & 63, tr = tid >> 6;
        const int d = d0 + dl, lt0 = tr * 16;
        const float w0 = cw[d * 4 + 0], w1 = cw[d * 4 + 1], w2 = cw[d * 4 + 2], w3 = cw[d * 4 + 3];
        const float bias = cb[d];
        float x0 = __builtin_bit_cast(float, xs[(lt0 + 0) * 65 + dl]);
        float x1 = __builtin_bit_cast(float, xs[(lt0 + 1) * 65 + dl]);
        float x2 = __builtin_bit_cast(float, xs[(lt0 + 2) * 65 + dl]);
        unsigned short o[16];
#pragma unroll
        for (int i = 0; i < 16; ++i) {
            float x3 = __builtin_bit_cast(float, xs[(lt0 + 3 + i) * 65 + dl]);
            float a = bias + w0 * x0 + w1 * x1 + w2 * x2 + w3 * x3;
            unsigned short us = f2b(a / (1.f + __expf(-a)));
            o[i] = us;
            ob[(lt0 + i) * 65 + dl] = us;
            x0 = x1; x1 = x2; x2 = x3;
        }
        unsigned short* dst = u_T + (size_t)d * NTOK + t0 + lt0;
        *(bf16x8*)(dst)     = *(bf16x8*)(o);
        *(bf16x8*)(dst + 8) = *(bf16x8*)(o + 8);
    }
    __syncthreads();
#pragma unroll
    for (int it = 0; it < 2; ++it) {
        int k = tid + it * 256;
        int t = k >> 3, d8 = (k & 7) * 8;
        unsigned short o[8];
#pragma unroll
        for (int j = 0; j < 8; ++j) o[j] = (unsigned short)ob[t * 65 + d8 + j];
        *(i32x4*)(u_row + (size_t)(t0 + t) * D_INNER + d0 + d8) = *(const i32x4*)o;
    }
}

// ---------------- bf16 MFMA GEMM with global_load_lds staging ----------------
// C[M,N] = A[M,K] * B[N,K]^T, A,B bf16 row-major. Linear LDS [128][32] (m97 structure).
// EPI 0: row-major f32 partial store (split-K via blockIdx.z plane offset)
// EPI 1: dt_proj epilogue (packed ddu + uD, transposed)
// EPI 3: in_proj epilogue (xi_T / z_b transposed bf16)
template <int EPI>
__global__ __launch_bounds__(256) void gemm_mfma(
    const unsigned short* __restrict__ A, const unsigned short* __restrict__ B,
    void* __restrict__ C, void* __restrict__ C2,
    int M, int N, int K, int lda, int ldb, int ldc,
    const float* __restrict__ bias, const float* __restrict__ res,
    const float* __restrict__ aux) {
    __shared__ unsigned short As[128 * 32];   // 8 KB, linear row-major, 64B/row
    __shared__ unsigned short Bs[128 * 32];
    const int tid = threadIdx.x;
    const int m0 = blockIdx.y * 128, n0 = blockIdx.x * 128;
    const int lane = tid & 63, wave = tid >> 6;
    const int wr = (wave >> 1) * 64, wc = (wave & 1) * 64;
    const int fr = lane & 15, fk = (lane >> 4) * 8;
    const int kspan = K / gridDim.z;
    const int kb = blockIdx.z * kspan;
    // per-lane staging source offsets: inst q covers rows q*16 + (lane>>2), col (lane&3)*8
    const int srow = lane >> 2, sc8 = (lane & 3) * 8;
    f32x4 acc[4][4] = {};
    for (int k0 = kb; k0 < kb + kspan; k0 += 32) {
#pragma unroll
        for (int i = 0; i < 2; ++i) {
            int q = wave + 4 * i;
            int row = q * 16 + srow;
            gload16(A + (size_t)(m0 + row) * lda + k0 + sc8, (unsigned short*)As + q * 512);
            gload16(B + (size_t)(n0 + row) * ldb + k0 + sc8, (unsigned short*)Bs + q * 512);
        }
        __syncthreads();          // compiler emits vmcnt(0) drain before barrier
        bf16x8 af[4], bfr[4];
#pragma unroll
        for (int i = 0; i < 4; ++i) af[i]  = *(const bf16x8*)&As[(wr + i * 16 + fr) * 32 + fk];
#pragma unroll
        for (int j = 0; j < 4; ++j) bfr[j] = *(const bf16x8*)&Bs[(wc + j * 16 + fr) * 32 + fk];
#pragma unroll
        for (int i = 0; i < 4; ++i)
#pragma unroll
            for (int j = 0; j < 4; ++j)
                acc[i][j] = __builtin_amdgcn_mfma_f32_16x16x32_bf16(af[i], bfr[j], acc[i][j], 0, 0, 0);
        __syncthreads();
    }
    const int er = (lane >> 4) * 4;
    if (EPI == 3) {
        unsigned short* xiT = (unsigned short*)C;
        unsigned short* zT  = (unsigned short*)C2;
#pragma unroll
        for (int i = 0; i < 4; ++i)
#pragma unroll
            for (int j = 0; j < 4; ++j) {
                int row0 = m0 + wr + i * 16 + er;
                int col = n0 + wc + j * 16 + fr;
                unsigned short* dst = (col < D_INNER)
                    ? xiT + (size_t)col * NTOK + row0
                    : zT + (size_t)(col - D_INNER) * NTOK + row0;
                unsigned short o[4];
#pragma unroll
                for (int r = 0; r < 4; ++r) o[r] = f2b(acc[i][j][r]);
                *(unsigned long long*)dst = *(unsigned long long*)o;
            }
    } else if (EPI == 1) {
        const unsigned short* uT = (const unsigned short*)res;   // u_T bf16, [d][token]
        unsigned int* ddu = (unsigned int*)C;
        unsigned short* uDb = (unsigned short*)C2;
#pragma unroll
        for (int i = 0; i < 4; ++i)
#pragma unroll
            for (int j = 0; j < 4; ++j) {
                int row0 = m0 + wr + i * 16 + er;
                int col = n0 + wc + j * 16 + fr;
                float bb = bias[col];
                float Dv = aux[col];
                u16x4 uu = *(const u16x4*)(uT + (size_t)col * NTOK + row0);
                i32x4 pk;
                unsigned short ud[4];
#pragma unroll
                for (int r = 0; r < 4; ++r) {
                    float t = acc[i][j][r] + bb;
                    float v = fmaxf(t, 0.f) + log1pf(expf(-fabsf(t)));   // softplus
                    float uf = b2f(uu[r]);
                    pk[r] = (int)(((unsigned)f2b(v)) | (((unsigned)f2b(v * uf)) << 16));
                    ud[r] = f2b(uf * Dv);
                }
                *(i32x4*)(ddu + (size_t)col * ldc + row0) = pk;
                *(unsigned long long*)(uDb + (size_t)col * ldc + row0) = *(unsigned long long*)ud;
            }
    } else {
        float* Cs = (float*)C + (size_t)blockIdx.z * M * ldc;
#pragma unroll
        for (int i = 0; i < 4; ++i)
#pragma unroll
            for (int j = 0; j < 4; ++j) {
                int col = n0 + wc + j * 16 + fr;
                if (col < N) {
#pragma unroll
                    for (int r = 0; r < 4; ++r) {
                        int row = m0 + wr + i * 16 + er + r;
                        Cs[(size_t)row * ldc + col] = acc[i][j][r];
                    }
                }
            }
    }
}

// ---------------- out_proj split-K combine + residual ----------------
__global__ void combine_residual(const float* __restrict__ part, const float* __restrict__ x,
                                 float* __restrict__ out) {
    int i = blockIdx.x * 256 + threadIdx.x;
    f32x4 s = *(const f32x4*)(x + (size_t)i * 4);
#pragma unroll
    for (int z = 0; z < 4; ++z)
        s += *(const f32x4*)(part + (size_t)z * NTOK * DIMX + (size_t)i * 4);
    *(f32x4*)(out + (size_t)i * 4) = s;
}

// ---------------- x_proj split-K combine ----------------
__global__ void xproj_combine(const float* __restrict__ xp, unsigned short* __restrict__ xdbl_b,
                              float* __restrict__ B_T, float* __restrict__ C_T) {
    int row = blockIdx.x;
    int col = threadIdx.x;
    if (col >= 96) return;
    float s = 0.f;
#pragma unroll
    for (int p = 0; p < 8; ++p) s += xp[(size_t)p * NTOK * 96 + (size_t)row * 96 + col];
    if (col < 64) xdbl_b[row * 64 + col] = f2b(s);
    else if (col < 80) B_T[(size_t)(col - 64) * NTOK + row] = s;
    else C_T[(size_t)(col - 80) * NTOK + row] = s;
}

// ================= Chunked selective scan (R10/R12 best config) =================

struct G1 { i32x4 p0, p1; f32x4 b0, b1; };

__device__ __forceinline__ void g1_load(G1& G, const unsigned int* pp, const float* pb, int g8) {
    G.p0 = *(const i32x4*)(pp + g8); G.p1 = *(const i32x4*)(pp + g8 + 4);
    G.b0 = *(const f32x4*)(pb + g8); G.b1 = *(const f32x4*)(pb + g8 + 4);
}
__device__ __forceinline__ void g1_proc(const G1& G, float& h, float& Pr, float A2) {
    float e[8], g[8];
#pragma unroll
    for (int q = 0; q < 8; ++q) {
        unsigned int v = (unsigned int)((q < 4) ? G.p0[q] : G.p1[q - 4]);
        float bq = (q < 4) ? G.b0[q] : G.b1[q - 4];
        e[q] = exp2f(lo2f(v) * A2);
        g[q] = hi2f(v) * bq;
    }
#pragma unroll
    for (int q = 0; q < 8; ++q) h = e[q] * h + g[q];
    float ee = ((e[0] * e[1]) * (e[2] * e[3])) * ((e[4] * e[5]) * (e[6] * e[7]));
    Pr *= ee;
}

__global__ __launch_bounds__(256) void scan_pass1(
    const unsigned int* __restrict__ ddu, const float* __restrict__ B_T,
    const float* __restrict__ A_log, float* __restrict__ hl, float* __restrict__ Pc) {
    const int tid = threadIdx.x, lane = tid & 63;
    const int s = lane & 15;
    const int chunk = blockIdx.x & (NC - 1), grp = blockIdx.x >> 4;
    const int gchan = grp * 16 + (tid >> 6) * 4 + (lane >> 4);
    const int b = gchan >> 11, d = gchan & (D_INNER - 1);
    const float A2 = -__expf(A_log[d * D_STATE + s]) * LOG2E;
    const int tb = b * L_SEQ + chunk * LC;
    const unsigned int* pp = ddu + (size_t)d * NTOK + tb;
    const float* pb = B_T + (size_t)s * NTOK + tb;
    float h = 0.f, Pr = 1.f;
    G1 ga, gb, gc;
    g1_load(ga, pp, pb, 0);
    g1_load(gb, pp, pb, 8);
    g1_load(gc, pp, pb, 16);
    g1_proc(ga, h, Pr, A2); g1_load(ga, pp, pb, 24);
    g1_proc(gb, h, Pr, A2); g1_load(gb, pp, pb, 32);
    g1_proc(gc, h, Pr, A2); g1_load(gc, pp, pb, 40);
    g1_proc(ga, h, Pr, A2); g1_load(ga, pp, pb, 48);
    g1_proc(gb, h, Pr, A2); g1_load(gb, pp, pb, 56);
    g1_proc(gc, h, Pr, A2);
    g1_proc(ga, h, Pr, A2);
    g1_proc(gb, h, Pr, A2);
    int o = chunk * NLANE + gchan * D_STATE + s;
    hl[o] = h;
    Pc[o] = Pr;
}

__global__ __launch_bounds__(256) void scan_pass2(const float* __restrict__ hl,
                                                  const float* __restrict__ Pc,
                                                  float* __restrict__ hi) {
    int gid = blockIdx.x * 256 + threadIdx.x;
    float h = 0.f;
    hi[gid] = 0.f;
#pragma unroll
    for (int c = 1; c < NC; ++c) {
        h = hl[(c - 1) * NLANE + gid] + Pc[(c - 1) * NLANE + gid] * h;
        hi[c * NLANE + gid] = h;
    }
}

struct G3 { i32x4 p0, p1; f32x4 b0, b1, c0, c1; };

__device__ __forceinline__ void g3_load(G3& G, const unsigned int* pp,
                                        const float* pb, const float* pc, int g8) {
    G.p0 = *(const i32x4*)(pp + g8); G.p1 = *(const i32x4*)(pp + g8 + 4);
    G.b0 = *(const f32x4*)(pb + g8); G.b1 = *(const f32x4*)(pb + g8 + 4);
    G.c0 = *(const f32x4*)(pc + g8); G.c1 = *(const f32x4*)(pc + g8 + 4);
}

__device__ __forceinline__ void g3_proc(const G3& G, float& h, float A2, int s,
                                        const unsigned short* puD, const unsigned short* pz,
                                        unsigned short* pyT, int g8) {
    float e[8], g[8];
#pragma unroll
    for (int q = 0; q < 8; ++q) {
        unsigned int v = (unsigned int)((q < 4) ? G.p0[q] : G.p1[q - 4]);
        float bq = (q < 4) ? G.b0[q] : G.b1[q - 4];
        e[q] = exp2f(lo2f(v) * A2);
        g[q] = hi2f(v) * bq;
    }
    float y[8];
#pragma unroll
    for (int q = 0; q < 8; ++q) {
        h = e[q] * h + g[q];
        float cq = (q < 4) ? G.c0[q] : G.c1[q - 4];
        y[q] = h * cq;
    }
    const bool b4 = (s & 4) != 0, b2_ = (s & 2) != 0, b1 = (s & 1) != 0;
#pragma unroll
    for (int i = 0; i < 4; ++i) {
        float give = b4 ? y[i] : y[i + 4];
        float keep = b4 ? y[i + 4] : y[i];
        y[i] = keep + __shfl_xor(give, 4);
    }
#pragma unroll
    for (int i = 0; i < 2; ++i) {
        float give = b2_ ? y[i] : y[i + 2];
        float keep = b2_ ? y[i + 2] : y[i];
        y[i] = keep + __shfl_xor(give, 2);
    }
    {
        float give = b1 ? y[0] : y[1];
        float keep = b1 ? y[1] : y[0];
        y[0] = keep + __shfl_xor(give, 1);
    }
    y[0] += __shfl_xor(y[0], 8);
    if (!(s & 8)) {
        int q = s & 7;
        float zz = b2f(pz[g8 + q]);
        float yy = y[0] + b2f(puD[g8 + q]);
        pyT[g8 + q] = f2b(yy * (zz / (1.f + __expf(-zz))));
    }
}

__global__ __launch_bounds__(256) void scan_pass3(
    const unsigned int* __restrict__ ddu, const float* __restrict__ B_T,
    const float* __restrict__ C_T, const unsigned short* __restrict__ uD_b,
    const unsigned short* __restrict__ z_b, const float* __restrict__ A_log,
    const float* __restrict__ hi, unsigned short* __restrict__ y_T) {
    const int tid = threadIdx.x, lane = tid & 63;
    const int s = lane & 15;
    const int chunk = blockIdx.x & (NC - 1), grp = blockIdx.x >> 4;
    const int gchan = grp * 16 + (tid >> 6) * 4 + (lane >> 4);
    const int b = gchan >> 11, d = gchan & (D_INNER - 1);
    const float A2 = -__expf(A_log[d * D_STATE + s]) * LOG2E;
    const int tb = b * L_SEQ + chunk * LC;
    const unsigned int* pp = ddu + (size_t)d * NTOK + tb;
    const float* pb = B_T + (size_t)s * NTOK + tb;
    const float* pc = C_T + (size_t)s * NTOK + tb;
    const unsigned short* puD = uD_b + (size_t)d * NTOK + tb;
    const unsigned short* pz = z_b + (size_t)d * NTOK + tb;
    unsigned short* pyT = y_T + (size_t)d * NTOK + tb;
    float h = hi[chunk * NLANE + gchan * D_STATE + s];
    G3 ga, gb, gc;
    g3_load(ga, pp, pb, pc, 0);
    g3_load(gb, pp, pb, pc, 8);
    g3_load(gc, pp, pb, pc, 16);
    g3_proc(ga, h, A2, s, puD, pz, pyT, 0);  g3_load(ga, pp, pb, pc, 24);
    g3_proc(gb, h, A2, s, puD, pz, pyT, 8);  g3_load(gb, pp, pb, pc, 32);
    g3_proc(gc, h, A2, s, puD, pz, pyT, 16); g3_load(gc, pp, pb, pc, 40);
    g3_proc(ga, h, A2, s, puD, pz, pyT, 24); g3_load(ga, pp, pb, pc, 48);
    g3_proc(gb, h, A2, s, puD, pz, pyT, 32); g3_load(gb, pp, pb, pc, 56);
    g3_proc(gc, h, A2, s, puD, pz, pyT, 40);
    g3_proc(ga, h, A2, s, puD, pz, pyT, 48);
    g3_proc(gb, h, A2, s, puD, pz, pyT, 56);
}

extern "C" void kernel_launch(void* const* d_in, const int* in_sizes, int n_in,
                              void* d_out, int out_size, void* d_ws, size_t ws_size,
                              hipStream_t stream) {
    const float* x          = (const float*)d_in[0];
    const float* norm_w     = (const float*)d_in[1];
    const float* in_proj_w  = (const float*)d_in[2];
    const float* conv_w     = (const float*)d_in[3];
    const float* conv_b     = (const float*)d_in[4];
    const float* x_proj_w   = (const float*)d_in[5];
    const float* dt_proj_w  = (const float*)d_in[6];
    const float* dt_proj_b  = (const float*)d_in[7];
    const float* A_log      = (const float*)d_in[8];
    const float* D_param    = (const float*)d_in[9];
    const float* out_proj_w = (const float*)d_in[10];
    float* out = (float*)d_out;

    char* p = (char*)d_ws;
    unsigned short* xi_T = (unsigned short*)p; p += (size_t)D_INNER * NTOK * 2;   // 8.39 MB
    unsigned short* z_b  = (unsigned short*)p; p += (size_t)D_INNER * NTOK * 2;   // 8.39 MB
    unsigned int*   ddu  = (unsigned int*)p;   p += (size_t)D_INNER * NTOK * 4;   // 16.78 MB
    unsigned short* u_T  = (unsigned short*)p; p += (size_t)D_INNER * NTOK * 2;   // 8.39 MB
    unsigned short* uD_b = (unsigned short*)p; p += (size_t)D_INNER * NTOK * 2;   // 8.39 MB
    unsigned short* y_T  = (unsigned short*)p; p += (size_t)D_INNER * NTOK * 2;   // 8.39 MB
    unsigned short* xdbl_b = (unsigned short*)p; p += (size_t)NTOK * 64 * 2;      // 0.26 MB
    float* B_T = (float*)p;  p += (size_t)D_STATE * NTOK * 4;                     // 0.13 MB
    float* C_T = (float*)p;  p += (size_t)D_STATE * NTOK * 4;                     // 0.13 MB
    unsigned short* xn_b = (unsigned short*)p; p += (size_t)NTOK * DIMX * 2;      // 4.19 MB
    unsigned short* w_in_b  = (unsigned short*)p; p += (size_t)2 * D_INNER * DIMX * 2;  // 8.39 MB
    unsigned short* w_x_b   = (unsigned short*)p; p += (size_t)96 * D_INNER * 2;
    unsigned short* w_dt_b  = (unsigned short*)p; p += (size_t)D_INNER * DT_RANK * 2;
    unsigned short* w_out_b = (unsigned short*)p; p += (size_t)DIMX * D_INNER * 2;

    // overlays (disjoint lifetimes):
    float* xp_part = (float*)y_T;              // 6.29 MB (y_T written only by pass3)
    float* hl = (float*)w_in_b;                // 4.19 MB (w_in dead after in_proj; pass1+)
    float* Pc = hl + NC * NLANE;               // 4.19 MB
    float* hi = (float*)xn_b;                  // 4.19 MB (xn dead after in_proj; pass2+)
    unsigned short* u_row = (unsigned short*)w_in_b;  // 8.39 MB (post-conv .. x_proj, before hl/Pc)
    float* out_part = (float*)ddu;             // 33.5 MB = ddu+u_T+uD_b (all dead after pass3)

    // 0. all weight conversions f32 -> bf16 (one kernel)
    f2b_all<<<(N1C + N2C + N3C + N4C + 255) / 256, 256, 0, stream>>>(
        in_proj_w, x_proj_w, dt_proj_w, out_proj_w, w_in_b, w_x_b, w_dt_b, w_out_b);

    // 1. RMSNorm -> bf16
    rmsnorm_kernel<<<NTOK, 256, 0, stream>>>(x, norm_w, xn_b);
    // 2. in_proj: xi_T bf16 [d][t] + z_b bf16 [d][t]
    gemm_mfma<3><<<dim3(32, 16), 256, 0, stream>>>(xn_b, w_in_b, xi_T, z_b,
        NTOK, 2 * D_INNER, DIMX, DIMX, DIMX, NTOK, nullptr, nullptr, nullptr);
    // 3. FUSED conv + SiLU -> u_T [d][t] AND u_row [t][d]
    conv_silu_tr<<<dim3(NTOK / 64, D_INNER / 64), 256, 0, stream>>>(
        xi_T, conv_w, conv_b, u_T, u_row);
    // 4. x_proj split-K=8 partials + combine
    gemm_mfma<0><<<dim3(1, 16, 8), 256, 0, stream>>>(u_row, w_x_b, xp_part, nullptr,
        NTOK, 96, D_INNER, D_INNER, D_INNER, 96, nullptr, nullptr, nullptr);
    xproj_combine<<<NTOK, 128, 0, stream>>>(xp_part, xdbl_b, B_T, C_T);
    // 5. dt_proj: ddu (packed bf16 delta,du) + uD_b (u*D)  [all transposed]
    gemm_mfma<1><<<dim3(16, 16), 256, 0, stream>>>(xdbl_b, w_dt_b, ddu, uD_b,
        NTOK, D_INNER, DT_RANK, 64, DT_RANK, NTOK, dt_proj_b, (const float*)u_T, D_param);
    // 6. chunked selective scan (gate fused into pass 3, transposed y)
    scan_pass1<<<4096, 256, 0, stream>>>(ddu, B_T, A_log, hl, Pc);
    scan_pass2<<<NLANE / 256, 256, 0, stream>>>(hl, Pc, hi);
    scan_pass3<<<4096, 256, 0, stream>>>(ddu, B_T, C_T, uD_b, z_b, A_log, hi, y_T);
    // 6b. transpose y_T -> y_row [t][d]  (xi_T dead after conv)
    transpose_bf16<<<dim3(NTOK / 64, D_INNER / 64), 256, 0, stream>>>(y_T, xi_T, D_INNER, NTOK);
    // 7. out_proj split-K=4 -> partials (ddu/u_T/uD_b region dead after pass3)
    gemm_mfma<0><<<dim3(8, 16, 4), 256, 0, stream>>>(xi_T, w_out_b, out_part, nullptr,
        NTOK, DIMX, D_INNER, D_INNER, D_INNER, DIMX, nullptr, nullptr, nullptr);
    // 8. combine partials + residual -> out
    combine_residual<<<NTOK * DIMX / 4 / 256, 256, 0, stream>>>(out_part, x, out);
}

// Round 14
// 209.348 us; speedup vs baseline: 1.2699x; 1.1478x over previous
//
#include <hip/hip_runtime.h>
#include <math.h>

#define DIMX 1024
#define D_STATE 16
#define D_INNER 2048
#define DT_RANK 64
#define B_SZ 2
#define L_SEQ 1024
#define NTOK (B_SZ * L_SEQ)
#define EPSR 1e-5f
#define NC 32          // chunks per sequence
#define LC 32          // steps per chunk
#define NCH (B_SZ * D_INNER)            // 4096 channels
#define NLANE (NCH * D_STATE)           // 65536 (chan,state) pairs
#define LOG2E 1.44269504f

typedef __attribute__((ext_vector_type(8))) short bf16x8;
typedef __attribute__((ext_vector_type(4))) int   i32x4;
typedef __attribute__((ext_vector_type(4))) float f32x4;
typedef __attribute__((ext_vector_type(4))) unsigned short u16x4;

__device__ __forceinline__ unsigned short f2b(float f) {
    unsigned int u = __builtin_bit_cast(unsigned int, f);
    u += 0x7fffu + ((u >> 16) & 1u);          // RNE
    return (unsigned short)(u >> 16);
}
__device__ __forceinline__ float b2f(unsigned short h) {
    unsigned int u = ((unsigned int)h) << 16;
    return __builtin_bit_cast(float, u);
}
__device__ __forceinline__ float lo2f(unsigned int v) {       // low bf16 -> f32
    return __builtin_bit_cast(float, v << 16);
}
__device__ __forceinline__ float hi2f(unsigned int v) {       // high bf16 -> f32
    return __builtin_bit_cast(float, v & 0xffff0000u);
}
// async global->LDS, 16B per lane, wave-uniform LDS base + lane*16
__device__ __forceinline__ void gload16(const void* g, void* l) {
    __builtin_amdgcn_global_load_lds(
        (const __attribute__((address_space(1))) unsigned int*)g,
        (__attribute__((address_space(3))) unsigned int*)l, 16, 0, 0);
}

// ---------------- all-weights f32 -> bf16 conversion (one kernel) ----------------
#define N1C (2 * D_INNER * DIMX / 4)
#define N2C (96 * D_INNER / 4)
#define N3C (D_INNER * DT_RANK / 4)
#define N4C (DIMX * D_INNER / 4)
__global__ void f2b_all(const float* __restrict__ w_in, const float* __restrict__ w_x,
                        const float* __restrict__ w_dt, const float* __restrict__ w_out,
                        unsigned short* __restrict__ o_in, unsigned short* __restrict__ o_x,
                        unsigned short* __restrict__ o_dt, unsigned short* __restrict__ o_out) {
    int i = blockIdx.x * 256 + threadIdx.x;
    const float* src; unsigned short* dst; int j;
    if (i < N1C)                       { src = w_in;  dst = o_in;  j = i; }
    else if (i < N1C + N2C)            { src = w_x;   dst = o_x;   j = i - N1C; }
    else if (i < N1C + N2C + N3C)      { src = w_dt;  dst = o_dt;  j = i - N1C - N2C; }
    else if (i < N1C + N2C + N3C + N4C){ src = w_out; dst = o_out; j = i - N1C - N2C - N3C; }
    else return;
    f32x4 v = *(const f32x4*)(src + (size_t)j * 4);
    unsigned short o[4];
#pragma unroll
    for (int k = 0; k < 4; ++k) o[k] = f2b(v[k]);
    *(unsigned long long*)(dst + (size_t)j * 4) = *(unsigned long long*)o;
}

// ---------------- RMSNorm ----------------
__global__ void rmsnorm_kernel(const float* __restrict__ x, const float* __restrict__ w,
                               unsigned short* __restrict__ xnb) {
    int row = blockIdx.x;
    const float* xr = x + (size_t)row * DIMX;
    unsigned short* outr = xnb + (size_t)row * DIMX;
    int t = threadIdx.x;
    float v[4];
    float ss = 0.f;
#pragma unroll
    for (int i = 0; i < 4; ++i) { v[i] = xr[t + i * 256]; ss += v[i] * v[i]; }
#pragma unroll
    for (int off = 32; off > 0; off >>= 1) ss += __shfl_down(ss, off);
    __shared__ float red[4];
    if ((t & 63) == 0) red[t >> 6] = ss;
    __syncthreads();
    float tot = red[0] + red[1] + red[2] + red[3];
    float scale = rsqrtf(tot * (1.f / DIMX) + EPSR);
#pragma unroll
    for (int i = 0; i < 4; ++i) outr[t + i * 256] = f2b(v[i] * scale * w[t + i * 256]);
}

// ---------------- FUSED depthwise causal conv + SiLU -> u_row [t][d] ----------------
__global__ __launch_bounds__(256) void conv_silu_tr(
    const unsigned short* __restrict__ xiT, const float* __restrict__ cw,
    const float* __restrict__ cb, unsigned short* __restrict__ u_row) {
    __shared__ unsigned int xs[67 * 65];
    __shared__ unsigned int ob[64 * 65];
    const int t0 = blockIdx.x * 64;
    const int d0 = blockIdx.y * 64;
    const int bstart = t0 & ~(L_SEQ - 1);
    const int tid = threadIdx.x;
    for (int task = tid; task < 576; task += 256) {
        int d = task & 63, c = task >> 6;
        int tc = t0 - 8 + c * 8;
        int tl = tc < 0 ? 0 : tc;
        i32x4 v = *(const i32x4*)(xiT + (size_t)(d0 + d) * NTOK + tl);
        const unsigned short* vs = (const unsigned short*)&v;
#pragma unroll
        for (int i = 0; i < 8; ++i) {
            int t = tc + i;
            int row = t - (t0 - 3);
            if (row >= 0 && row < 67) {
                float xv = (t >= bstart) ? b2f(vs[i]) : 0.f;
                xs[row * 65 + d] = __builtin_bit_cast(unsigned int, xv);
            }
        }
    }
    __syncthreads();
    {
        const int dl = tid & 63, tr = tid >> 6;
        const int d = d0 + dl, lt0 = tr * 16;
        const float w0 = cw[d * 4 + 0], w1 = cw[d * 4 + 1], w2 = cw[d * 4 + 2], w3 = cw[d * 4 + 3];
        const float bias = cb[d];
        float x0 = __builtin_bit_cast(float, xs[(lt0 + 0) * 65 + dl]);
        float x1 = __builtin_bit_cast(float, xs[(lt0 + 1) * 65 + dl]);
        float x2 = __builtin_bit_cast(float, xs[(lt0 + 2) * 65 + dl]);
#pragma unroll
        for (int i = 0; i < 16; ++i) {
            float x3 = __builtin_bit_cast(float, xs[(lt0 + 3 + i) * 65 + dl]);
            float a = bias + w0 * x0 + w1 * x1 + w2 * x2 + w3 * x3;
            ob[(lt0 + i) * 65 + dl] = f2b(a / (1.f + __expf(-a)));
            x0 = x1; x1 = x2; x2 = x3;
        }
    }
    __syncthreads();
#pragma unroll
    for (int it = 0; it < 2; ++it) {
        int k = tid + it * 256;
        int t = k >> 3, d8 = (k & 7) * 8;
        unsigned short o[8];
#pragma unroll
        for (int j = 0; j < 8; ++j) o[j] = (unsigned short)ob[t * 65 + d8 + j];
        *(i32x4*)(u_row + (size_t)(t0 + t) * D_INNER + d0 + d8) = *(const i32x4*)o;
    }
}

// ---------------- bf16 MFMA GEMM with global_load_lds staging ----------------
// C[M,N] = A[M,K] * B[N,K]^T, A,B bf16 row-major. Linear LDS [128][32] (m97 structure).
// EPI 0: row-major f32 partial store (split-K via blockIdx.z plane offset)
// EPI 1: dt_proj: delta=softplus(acc+bias[col]); ddu[t][d] u32 pack(delta, delta*u);
//        uD[t][d] bf16 = u*D  (res = u_row bf16, aux = D_param)
// EPI 3: in_proj: col<2048 -> xi_T [d][t] bf16; col>=2048 -> z_row [t][d] bf16
template <int EPI>
__global__ __launch_bounds__(256) void gemm_mfma(
    const unsigned short* __restrict__ A, const unsigned short* __restrict__ B,
    void* __restrict__ C, void* __restrict__ C2,
    int M, int N, int K, int lda, int ldb, int ldc,
    const float* __restrict__ bias, const float* __restrict__ res,
    const float* __restrict__ aux) {
    __shared__ unsigned short As[128 * 32];
    __shared__ unsigned short Bs[128 * 32];
    const int tid = threadIdx.x;
    const int m0 = blockIdx.y * 128, n0 = blockIdx.x * 128;
    const int lane = tid & 63, wave = tid >> 6;
    const int wr = (wave >> 1) * 64, wc = (wave & 1) * 64;
    const int fr = lane & 15, fk = (lane >> 4) * 8;
    const int kspan = K / gridDim.z;
    const int kb = blockIdx.z * kspan;
    const int srow = lane >> 2, sc8 = (lane & 3) * 8;
    f32x4 acc[4][4] = {};
    for (int k0 = kb; k0 < kb + kspan; k0 += 32) {
#pragma unroll
        for (int i = 0; i < 2; ++i) {
            int q = wave + 4 * i;
            int row = q * 16 + srow;
            gload16(A + (size_t)(m0 + row) * lda + k0 + sc8, (unsigned short*)As + q * 512);
            gload16(B + (size_t)(n0 + row) * ldb + k0 + sc8, (unsigned short*)Bs + q * 512);
        }
        __syncthreads();
        bf16x8 af[4], bfr[4];
#pragma unroll
        for (int i = 0; i < 4; ++i) af[i]  = *(const bf16x8*)&As[(wr + i * 16 + fr) * 32 + fk];
#pragma unroll
        for (int j = 0; j < 4; ++j) bfr[j] = *(const bf16x8*)&Bs[(wc + j * 16 + fr) * 32 + fk];
#pragma unroll
        for (int i = 0; i < 4; ++i)
#pragma unroll
            for (int j = 0; j < 4; ++j)
                acc[i][j] = __builtin_amdgcn_mfma_f32_16x16x32_bf16(af[i], bfr[j], acc[i][j], 0, 0, 0);
        __syncthreads();
    }
    const int er = (lane >> 4) * 4;
    if (EPI == 3) {
        unsigned short* xiT = (unsigned short*)C;
        unsigned short* zR  = (unsigned short*)C2;
#pragma unroll
        for (int i = 0; i < 4; ++i)
#pragma unroll
            for (int j = 0; j < 4; ++j) {
                int row0 = m0 + wr + i * 16 + er;
                int col = n0 + wc + j * 16 + fr;
                if (col < D_INNER) {
                    unsigned short o[4];
#pragma unroll
                    for (int r = 0; r < 4; ++r) o[r] = f2b(acc[i][j][r]);
                    *(unsigned long long*)(xiT + (size_t)col * NTOK + row0) = *(unsigned long long*)o;
                } else {
#pragma unroll
                    for (int r = 0; r < 4; ++r)
                        zR[(size_t)(row0 + r) * D_INNER + col - D_INNER] = f2b(acc[i][j][r]);
                }
            }
    } else if (EPI == 1) {
        const unsigned short* uR = (const unsigned short*)res;   // u_row bf16 [t][d]
        unsigned int* dduP = (unsigned int*)C;
        unsigned short* uDP = (unsigned short*)C2;
#pragma unroll
        for (int i = 0; i < 4; ++i)
#pragma unroll
            for (int j = 0; j < 4; ++j) {
                int row0 = m0 + wr + i * 16 + er;
                int col = n0 + wc + j * 16 + fr;
                float bb = bias[col];
                float Dv = aux[col];
#pragma unroll
                for (int r = 0; r < 4; ++r) {
                    size_t idx = (size_t)(row0 + r) * D_INNER + col;
                    float t = acc[i][j][r] + bb;
                    float v = fmaxf(t, 0.f) + log1pf(expf(-fabsf(t)));   // softplus
                    float uf = b2f(uR[idx]);
                    dduP[idx] = ((unsigned)f2b(v)) | (((unsigned)f2b(v * uf)) << 16);
                    uDP[idx] = f2b(uf * Dv);
                }
            }
    } else {
        float* Cs = (float*)C + (size_t)blockIdx.z * M * ldc;
#pragma unroll
        for (int i = 0; i < 4; ++i)
#pragma unroll
            for (int j = 0; j < 4; ++j) {
                int col = n0 + wc + j * 16 + fr;
                if (col < N) {
#pragma unroll
                    for (int r = 0; r < 4; ++r) {
                        int row = m0 + wr + i * 16 + er + r;
                        Cs[(size_t)row * ldc + col] = acc[i][j][r];
                    }
                }
            }
    }
}

// ---------------- out_proj split-K combine + residual ----------------
__global__ void combine_residual(const float* __restrict__ part, const float* __restrict__ x,
                                 float* __restrict__ out) {
    int i = blockIdx.x * 256 + threadIdx.x;
    f32x4 s = *(const f32x4*)(x + (size_t)i * 4);
#pragma unroll
    for (int z = 0; z < 4; ++z)
        s += *(const f32x4*)(part + (size_t)z * NTOK * DIMX + (size_t)i * 4);
    *(f32x4*)(out + (size_t)i * 4) = s;
}

// ---------------- x_proj split-K combine ----------------
__global__ void xproj_combine(const float* __restrict__ xp, unsigned short* __restrict__ xdbl_b,
                              float* __restrict__ B_T, float* __restrict__ C_T) {
    int row = blockIdx.x;
    int col = threadIdx.x;
    if (col >= 96) return;
    float s = 0.f;
#pragma unroll
    for (int p = 0; p < 8; ++p) s += xp[(size_t)p * NTOK * 96 + (size_t)row * 96 + col];
    if (col < 64) xdbl_b[row * 64 + col] = f2b(s);
    else if (col < 80) B_T[(size_t)(col - 64) * NTOK + row] = s;
    else C_T[(size_t)(col - 80) * NTOK + row] = s;
}

// ================= Chunked selective scan: lane = channel, states in registers =================
// Block = 256 threads = 256 channels, all on one chunk. Grid (NC, NCH/256).
// Token-major streams: ddu[t][d] u32, uD[t][d] bf16, z_row[t][d] bf16, y_row[t][d] bf16.
// B/C wave-uniform per step -> staged in LDS, broadcast reads.

__global__ __launch_bounds__(256) void scan_pass1(
    const unsigned int* __restrict__ ddu, const float* __restrict__ B_T,
    const float* __restrict__ A_log, float* __restrict__ hl, float* __restrict__ Pc) {
    __shared__ float bs[LC][16];
    const int tid = threadIdx.x;
    const int chunk = blockIdx.x;
    const int gchan = blockIdx.y * 256 + tid;
    const int b = gchan >> 11, d = gchan & (D_INNER - 1);
    const int tb = b * L_SEQ + chunk * LC;
    for (int v = tid; v < LC * 16; v += 256) {
        int t = v & (LC - 1), s = v >> 5;
        bs[t][s] = B_T[(size_t)s * NTOK + tb + t];
    }
    __syncthreads();
    float A2[D_STATE], h[D_STATE], Pr[D_STATE];
    const float* al = A_log + d * D_STATE;
#pragma unroll
    for (int s = 0; s < D_STATE; ++s) {
        A2[s] = -__expf(al[s]) * LOG2E;
        h[s] = 0.f; Pr[s] = 1.f;
    }
    const unsigned int* pd = ddu + (size_t)tb * D_INNER + d;
    unsigned int pf[LC];
#pragma unroll
    for (int t = 0; t < 3; ++t) pf[t] = pd[(size_t)t * D_INNER];
#pragma unroll
    for (int t = 0; t < LC; ++t) {
        if (t + 3 < LC) pf[t + 3] = pd[(size_t)(t + 3) * D_INNER];
        unsigned int v = pf[t];
        float dl = lo2f(v), du = hi2f(v);
        float barr[16];
        f32x4 b0 = *(const f32x4*)&bs[t][0];
        f32x4 b1 = *(const f32x4*)&bs[t][4];
        f32x4 b2 = *(const f32x4*)&bs[t][8];
        f32x4 b3 = *(const f32x4*)&bs[t][12];
#pragma unroll
        for (int q = 0; q < 4; ++q) { barr[q] = b0[q]; barr[4 + q] = b1[q]; barr[8 + q] = b2[q]; barr[12 + q] = b3[q]; }
#pragma unroll
        for (int s = 0; s < D_STATE; ++s) {
            float e = exp2f(dl * A2[s]);
            h[s] = e * h[s] + du * barr[s];
            Pr[s] *= e;
        }
    }
    float* ph = hl + (size_t)chunk * NLANE + (size_t)gchan * D_STATE;
    float* pp = Pc + (size_t)chunk * NLANE + (size_t)gchan * D_STATE;
#pragma unroll
    for (int q = 0; q < 4; ++q) {
        f32x4 hv = {h[4 * q], h[4 * q + 1], h[4 * q + 2], h[4 * q + 3]};
        f32x4 pv = {Pr[4 * q], Pr[4 * q + 1], Pr[4 * q + 2], Pr[4 * q + 3]};
        *(f32x4*)(ph + 4 * q) = hv;
        *(f32x4*)(pp + 4 * q) = pv;
    }
}

__global__ __launch_bounds__(256) void scan_pass2(const float* __restrict__ hl,
                                                  const float* __restrict__ Pc,
                                                  float* __restrict__ hi) {
    int gid = blockIdx.x * 256 + threadIdx.x;
    float h = 0.f;
    hi[gid] = 0.f;
#pragma unroll
    for (int c = 1; c < NC; ++c) {
        h = hl[(size_t)(c - 1) * NLANE + gid] + Pc[(size_t)(c - 1) * NLANE + gid] * h;
        hi[(size_t)c * NLANE + gid] = h;
    }
}

__global__ __launch_bounds__(256) void scan_pass3(
    const unsigned int* __restrict__ ddu, const float* __restrict__ B_T,
    const float* __restrict__ C_T, const unsigned short* __restrict__ uD,
    const unsigned short* __restrict__ z_row, const float* __restrict__ A_log,
    const float* __restrict__ hi, unsigned short* __restrict__ y_row) {
    __shared__ float bcs[LC][32];              // [t][0..15]=B, [t][16..31]=C
    const int tid = threadIdx.x;
    const int chunk = blockIdx.x;
    const int gchan = blockIdx.y * 256 + tid;
    const int b = gchan >> 11, d = gchan & (D_INNER - 1);
    const int tb = b * L_SEQ + chunk * LC;
    for (int v = tid; v < LC * 32; v += 256) {
        int t = v & (LC - 1), q = v >> 5;      // q 0..31
        bcs[t][q] = (q < 16) ? B_T[(size_t)q * NTOK + tb + t]
                             : C_T[(size_t)(q - 16) * NTOK + tb + t];
    }
    __syncthreads();
    float A2[D_STATE], h[D_STATE];
    const float* al = A_log + d * D_STATE;
#pragma unroll
    for (int s = 0; s < D_STATE; ++s) A2[s] = -__expf(al[s]) * LOG2E;
    const float* ph = hi + (size_t)chunk * NLANE + (size_t)gchan * D_STATE;
#pragma unroll
    for (int q = 0; q < 4; ++q) {
        f32x4 hv = *(const f32x4*)(ph + 4 * q);
#pragma unroll
        for (int r = 0; r < 4; ++r) h[4 * q + r] = hv[r];
    }
    const unsigned int* pd = ddu + (size_t)tb * D_INNER + d;
    const unsigned short* pu = uD + (size_t)tb * D_INNER + d;
    const unsigned short* pz = z_row + (size_t)tb * D_INNER + d;
    unsigned short* py = y_row + (size_t)tb * D_INNER + d;
    unsigned int pf[LC];
    unsigned short pfu[LC], pfz[LC];
#pragma unroll
    for (int t = 0; t < 3; ++t) {
        pf[t] = pd[(size_t)t * D_INNER];
        pfu[t] = pu[(size_t)t * D_INNER];
        pfz[t] = pz[(size_t)t * D_INNER];
    }
#pragma unroll
    for (int t = 0; t < LC; ++t) {
        if (t + 3 < LC) {
            pf[t + 3] = pd[(size_t)(t + 3) * D_INNER];
            pfu[t + 3] = pu[(size_t)(t + 3) * D_INNER];
            pfz[t + 3] = pz[(size_t)(t + 3) * D_INNER];
        }
        unsigned int v = pf[t];
        float dl = lo2f(v), du = hi2f(v);
        float barr[16], carr[16];
        f32x4 b0 = *(const f32x4*)&bcs[t][0];
        f32x4 b1 = *(const f32x4*)&bcs[t][4];
        f32x4 b2 = *(const f32x4*)&bcs[t][8];
        f32x4 b3 = *(const f32x4*)&bcs[t][12];
        f32x4 c0 = *(const f32x4*)&bcs[t][16];
        f32x4 c1 = *(const f32x4*)&bcs[t][20];
        f32x4 c2 = *(const f32x4*)&bcs[t][24];
        f32x4 c3 = *(const f32x4*)&bcs[t][28];
#pragma unroll
        for (int q = 0; q < 4; ++q) {
            barr[q] = b0[q]; barr[4 + q] = b1[q]; barr[8 + q] = b2[q]; barr[12 + q] = b3[q];
            carr[q] = c0[q]; carr[4 + q] = c1[q]; carr[8 + q] = c2[q]; carr[12 + q] = c3[q];
        }
        float y0 = 0.f, y1 = 0.f, y2 = 0.f, y3 = 0.f;
#pragma unroll
        for (int s = 0; s < D_STATE; ++s) {
            float e = exp2f(dl * A2[s]);
            h[s] = e * h[s] + du * barr[s];
            float yv = h[s] * carr[s];
            if ((s & 3) == 0) y0 += yv;
            else if ((s & 3) == 1) y1 += yv;
            else if ((s & 3) == 2) y2 += yv;
            else y3 += yv;
        }
        float y = (y0 + y1) + (y2 + y3);
        float yy = y + b2f(pfu[t]);
        float zz = b2f(pfz[t]);
        py[(size_t)t * D_INNER] = f2b(yy * (zz / (1.f + __expf(-zz))));
    }
}

extern "C" void kernel_launch(void* const* d_in, const int* in_sizes, int n_in,
                              void* d_out, int out_size, void* d_ws, size_t ws_size,
                              hipStream_t stream) {
    const float* x          = (const float*)d_in[0];
    const float* norm_w     = (const float*)d_in[1];
    const float* in_proj_w  = (const float*)d_in[2];
    const float* conv_w     = (const float*)d_in[3];
    const float* conv_b     = (const float*)d_in[4];
    const float* x_proj_w   = (const float*)d_in[5];
    const float* dt_proj_w  = (const float*)d_in[6];
    const float* dt_proj_b  = (const float*)d_in[7];
    const float* A_log      = (const float*)d_in[8];
    const float* D_param    = (const float*)d_in[9];
    const float* out_proj_w = (const float*)d_in[10];
    float* out = (float*)d_out;

    char* p = (char*)d_ws;
    unsigned short* xi_T  = (unsigned short*)p; p += (size_t)D_INNER * NTOK * 2;   // 8.39 MB
    unsigned short* z_row = (unsigned short*)p; p += (size_t)NTOK * D_INNER * 2;   // 8.39 MB
    unsigned int*   ddu   = (unsigned int*)p;   p += (size_t)NTOK * D_INNER * 4;   // 16.78 MB
    unsigned short* u_row = (unsigned short*)p; p += (size_t)NTOK * D_INNER * 2;   // 8.39 MB
    unsigned short* uD    = (unsigned short*)p; p += (size_t)NTOK * D_INNER * 2;   // 8.39 MB
    unsigned short* y_row = (unsigned short*)p; p += (size_t)NTOK * D_INNER * 2;   // 8.39 MB
    unsigned short* xdbl_b = (unsigned short*)p; p += (size_t)NTOK * 64 * 2;       // 0.26 MB
    float* B_T = (float*)p;  p += (size_t)D_STATE * NTOK * 4;                      // 0.13 MB
    float* C_T = (float*)p;  p += (size_t)D_STATE * NTOK * 4;                      // 0.13 MB
    unsigned short* xn_b = (unsigned short*)p; p += (size_t)NTOK * DIMX * 2;       // 4.19 MB
    unsigned short* w_in_b  = (unsigned short*)p; p += (size_t)2 * D_INNER * DIMX * 2;  // 8.39 MB
    unsigned short* w_x_b   = (unsigned short*)p; p += (size_t)96 * D_INNER * 2;
    unsigned short* w_dt_b  = (unsigned short*)p; p += (size_t)D_INNER * DT_RANK * 2;
    unsigned short* w_out_b = (unsigned short*)p; p += (size_t)DIMX * D_INNER * 2;

    // overlays (disjoint lifetimes):
    float* xp_part = (float*)y_row;            // 6.29 MB (y_row written only by pass3)
    float* hl = (float*)u_row;                 // 8.39 MB (u_row dead after dt_proj; pass1+)
    float* Pc = (float*)w_in_b;                // 8.39 MB (w_in dead after in_proj; pass1+)
    float* hi = (float*)xi_T;                  // 8.39 MB (xi_T dead after conv; pass2+)
    float* out_part = (float*)ddu;             // 33.5 MB = ddu+u_row(hl)+uD... use ddu+uD region:
    // NOTE: out_part needs 4 * 8.39 = 33.5 MB; ddu (16.78) + u_row/hl (8.39, dead after pass3)
    //       + uD (8.39, dead after pass3) are contiguous in this layout -> 33.5 MB ✓

    // 0. all weight conversions f32 -> bf16 (one kernel)
    f2b_all<<<(N1C + N2C + N3C + N4C + 255) / 256, 256, 0, stream>>>(
        in_proj_w, x_proj_w, dt_proj_w, out_proj_w, w_in_b, w_x_b, w_dt_b, w_out_b);

    // 1. RMSNorm -> bf16
    rmsnorm_kernel<<<NTOK, 256, 0, stream>>>(x, norm_w, xn_b);
    // 2. in_proj: xi_T bf16 [d][t] + z_row bf16 [t][d]
    gemm_mfma<3><<<dim3(32, 16), 256, 0, stream>>>(xn_b, w_in_b, xi_T, z_row,
        NTOK, 2 * D_INNER, DIMX, DIMX, DIMX, NTOK, nullptr, nullptr, nullptr);
    // 3. FUSED conv + SiLU -> u_row [t][d]
    conv_silu_tr<<<dim3(NTOK / 64, D_INNER / 64), 256, 0, stream>>>(
        xi_T, conv_w, conv_b, u_row);
    // 4. x_proj split-K=8 partials + combine
    gemm_mfma<0><<<dim3(1, 16, 8), 256, 0, stream>>>(u_row, w_x_b, xp_part, nullptr,
        NTOK, 96, D_INNER, D_INNER, D_INNER, 96, nullptr, nullptr, nullptr);
    xproj_combine<<<NTOK, 128, 0, stream>>>(xp_part, xdbl_b, B_T, C_T);
    // 5. dt_proj: ddu [t][d] (packed bf16 delta,du) + uD [t][d] (u*D)
    gemm_mfma<1><<<dim3(16, 16), 256, 0, stream>>>(xdbl_b, w_dt_b, ddu, uD,
        NTOK, D_INNER, DT_RANK, 64, DT_RANK, D_INNER, dt_proj_b, (const float*)u_row, D_param);
    // 6. chunked selective scan (lane=channel, states in registers)
    scan_pass1<<<dim3(NC, NCH / 256), 256, 0, stream>>>(ddu, B_T, A_log, hl, Pc);
    scan_pass2<<<NLANE / 256, 256, 0, stream>>>(hl, Pc, hi);
    scan_pass3<<<dim3(NC, NCH / 256), 256, 0, stream>>>(ddu, B_T, C_T, uD, z_row, A_log, hi, y_row);
    // 7. out_proj split-K=4 -> partials (ddu/hl/uD region dead after pass3)
    gemm_mfma<0><<<dim3(8, 16, 4), 256, 0, stream>>>(y_row, w_out_b, out_part, nullptr,
        NTOK, DIMX, D_INNER, D_INNER, D_INNER, DIMX, nullptr, nullptr, nullptr);
    // 8. combine partials + residual -> out
    combine_residual<<<NTOK * DIMX / 4 / 256, 256, 0, stream>>>(out_part, x, out);
}

// Round 15
// 187.755 us; speedup vs baseline: 1.4159x; 1.1150x over previous
//
#include <hip/hip_runtime.h>
#include <math.h>

#define DIMX 1024
#define D_STATE 16
#define D_INNER 2048
#define DT_RANK 64
#define B_SZ 2
#define L_SEQ 1024
#define NTOK (B_SZ * L_SEQ)
#define EPSR 1e-5f
#define NC 32          // chunks per sequence
#define LC 32          // steps per chunk
#define NCH (B_SZ * D_INNER)            // 4096 channels
#define NLANE (NCH * D_STATE)           // 65536 (chan,state) pairs
#define LOG2E 1.44269504f

typedef __attribute__((ext_vector_type(8))) short bf16x8;
typedef __attribute__((ext_vector_type(4))) int   i32x4;
typedef __attribute__((ext_vector_type(4))) float f32x4;
typedef __attribute__((ext_vector_type(4))) unsigned short u16x4;

__device__ __forceinline__ unsigned short f2b(float f) {
    unsigned int u = __builtin_bit_cast(unsigned int, f);
    u += 0x7fffu + ((u >> 16) & 1u);          // RNE
    return (unsigned short)(u >> 16);
}
__device__ __forceinline__ float b2f(unsigned short h) {
    unsigned int u = ((unsigned int)h) << 16;
    return __builtin_bit_cast(float, u);
}
__device__ __forceinline__ float lo2f(unsigned int v) {       // low bf16 -> f32
    return __builtin_bit_cast(float, v << 16);
}
__device__ __forceinline__ float hi2f(unsigned int v) {       // high bf16 -> f32
    return __builtin_bit_cast(float, v & 0xffff0000u);
}
// async global->LDS, 16B per lane, wave-uniform LDS base + lane*16
__device__ __forceinline__ void gload16(const void* g, void* l) {
    __builtin_amdgcn_global_load_lds(
        (const __attribute__((address_space(1))) unsigned int*)g,
        (__attribute__((address_space(3))) unsigned int*)l, 16, 0, 0);
}

// ---------------- all-weights f32 -> bf16 conversion (one kernel) ----------------
#define N1C (2 * D_INNER * DIMX / 4)
#define N2C (96 * D_INNER / 4)
#define N3C (D_INNER * DT_RANK / 4)
#define N4C (DIMX * D_INNER / 4)
__global__ void f2b_all(const float* __restrict__ w_in, const float* __restrict__ w_x,
                        const float* __restrict__ w_dt, const float* __restrict__ w_out,
                        unsigned short* __restrict__ o_in, unsigned short* __restrict__ o_x,
                        unsigned short* __restrict__ o_dt, unsigned short* __restrict__ o_out) {
    int i = blockIdx.x * 256 + threadIdx.x;
    const float* src; unsigned short* dst; int j;
    if (i < N1C)                       { src = w_in;  dst = o_in;  j = i; }
    else if (i < N1C + N2C)            { src = w_x;   dst = o_x;   j = i - N1C; }
    else if (i < N1C + N2C + N3C)      { src = w_dt;  dst = o_dt;  j = i - N1C - N2C; }
    else if (i < N1C + N2C + N3C + N4C){ src = w_out; dst = o_out; j = i - N1C - N2C - N3C; }
    else return;
    f32x4 v = *(const f32x4*)(src + (size_t)j * 4);
    unsigned short o[4];
#pragma unroll
    for (int k = 0; k < 4; ++k) o[k] = f2b(v[k]);
    *(unsigned long long*)(dst + (size_t)j * 4) = *(unsigned long long*)o;
}

// ---------------- RMSNorm ----------------
__global__ void rmsnorm_kernel(const float* __restrict__ x, const float* __restrict__ w,
                               unsigned short* __restrict__ xnb) {
    int row = blockIdx.x;
    const float* xr = x + (size_t)row * DIMX;
    unsigned short* outr = xnb + (size_t)row * DIMX;
    int t = threadIdx.x;
    float v[4];
    float ss = 0.f;
#pragma unroll
    for (int i = 0; i < 4; ++i) { v[i] = xr[t + i * 256]; ss += v[i] * v[i]; }
#pragma unroll
    for (int off = 32; off > 0; off >>= 1) ss += __shfl_down(ss, off);
    __shared__ float red[4];
    if ((t & 63) == 0) red[t >> 6] = ss;
    __syncthreads();
    float tot = red[0] + red[1] + red[2] + red[3];
    float scale = rsqrtf(tot * (1.f / DIMX) + EPSR);
#pragma unroll
    for (int i = 0; i < 4; ++i) outr[t + i * 256] = f2b(v[i] * scale * w[t + i * 256]);
}

// ---------------- FUSED depthwise causal conv + SiLU -> u_row [t][d] ----------------
__global__ __launch_bounds__(256) void conv_silu_tr(
    const unsigned short* __restrict__ xiT, const float* __restrict__ cw,
    const float* __restrict__ cb, unsigned short* __restrict__ u_row) {
    __shared__ unsigned int xs[67 * 65];
    __shared__ unsigned int ob[64 * 65];
    const int t0 = blockIdx.x * 64;
    const int d0 = blockIdx.y * 64;
    const int bstart = t0 & ~(L_SEQ - 1);
    const int tid = threadIdx.x;
    for (int task = tid; task < 576; task += 256) {
        int d = task & 63, c = task >> 6;
        int tc = t0 - 8 + c * 8;
        int tl = tc < 0 ? 0 : tc;
        i32x4 v = *(const i32x4*)(xiT + (size_t)(d0 + d) * NTOK + tl);
        const unsigned short* vs = (const unsigned short*)&v;
#pragma unroll
        for (int i = 0; i < 8; ++i) {
            int t = tc + i;
            int row = t - (t0 - 3);
            if (row >= 0 && row < 67) {
                float xv = (t >= bstart) ? b2f(vs[i]) : 0.f;
                xs[row * 65 + d] = __builtin_bit_cast(unsigned int, xv);
            }
        }
    }
    __syncthreads();
    {
        const int dl = tid & 63, tr = tid >> 6;
        const int d = d0 + dl, lt0 = tr * 16;
        const float w0 = cw[d * 4 + 0], w1 = cw[d * 4 + 1], w2 = cw[d * 4 + 2], w3 = cw[d * 4 + 3];
        const float bias = cb[d];
        float x0 = __builtin_bit_cast(float, xs[(lt0 + 0) * 65 + dl]);
        float x1 = __builtin_bit_cast(float, xs[(lt0 + 1) * 65 + dl]);
        float x2 = __builtin_bit_cast(float, xs[(lt0 + 2) * 65 + dl]);
#pragma unroll
        for (int i = 0; i < 16; ++i) {
            float x3 = __builtin_bit_cast(float, xs[(lt0 + 3 + i) * 65 + dl]);
            float a = bias + w0 * x0 + w1 * x1 + w2 * x2 + w3 * x3;
            ob[(lt0 + i) * 65 + dl] = f2b(a / (1.f + __expf(-a)));
            x0 = x1; x1 = x2; x2 = x3;
        }
    }
    __syncthreads();
#pragma unroll
    for (int it = 0; it < 2; ++it) {
        int k = tid + it * 256;
        int t = k >> 3, d8 = (k & 7) * 8;
        unsigned short o[8];
#pragma unroll
        for (int j = 0; j < 8; ++j) o[j] = (unsigned short)ob[t * 65 + d8 + j];
        *(i32x4*)(u_row + (size_t)(t0 + t) * D_INNER + d0 + d8) = *(const i32x4*)o;
    }
}

// ---------------- bf16 MFMA GEMM with global_load_lds staging ----------------
template <int EPI>
__global__ __launch_bounds__(256) void gemm_mfma(
    const unsigned short* __restrict__ A, const unsigned short* __restrict__ B,
    void* __restrict__ C, void* __restrict__ C2,
    int M, int N, int K, int lda, int ldb, int ldc,
    const float* __restrict__ bias, const float* __restrict__ res,
    const float* __restrict__ aux) {
    __shared__ unsigned short As[128 * 32];
    __shared__ unsigned short Bs[128 * 32];
    const int tid = threadIdx.x;
    const int m0 = blockIdx.y * 128, n0 = blockIdx.x * 128;
    const int lane = tid & 63, wave = tid >> 6;
    const int wr = (wave >> 1) * 64, wc = (wave & 1) * 64;
    const int fr = lane & 15, fk = (lane >> 4) * 8;
    const int kspan = K / gridDim.z;
    const int kb = blockIdx.z * kspan;
    const int srow = lane >> 2, sc8 = (lane & 3) * 8;
    f32x4 acc[4][4] = {};
    for (int k0 = kb; k0 < kb + kspan; k0 += 32) {
#pragma unroll
        for (int i = 0; i < 2; ++i) {
            int q = wave + 4 * i;
            int row = q * 16 + srow;
            gload16(A + (size_t)(m0 + row) * lda + k0 + sc8, (unsigned short*)As + q * 512);
            gload16(B + (size_t)(n0 + row) * ldb + k0 + sc8, (unsigned short*)Bs + q * 512);
        }
        __syncthreads();
        bf16x8 af[4], bfr[4];
#pragma unroll
        for (int i = 0; i < 4; ++i) af[i]  = *(const bf16x8*)&As[(wr + i * 16 + fr) * 32 + fk];
#pragma unroll
        for (int j = 0; j < 4; ++j) bfr[j] = *(const bf16x8*)&Bs[(wc + j * 16 + fr) * 32 + fk];
#pragma unroll
        for (int i = 0; i < 4; ++i)
#pragma unroll
            for (int j = 0; j < 4; ++j)
                acc[i][j] = __builtin_amdgcn_mfma_f32_16x16x32_bf16(af[i], bfr[j], acc[i][j], 0, 0, 0);
        __syncthreads();
    }
    const int er = (lane >> 4) * 4;
    if (EPI == 3) {
        unsigned short* xiT = (unsigned short*)C;
        unsigned short* zR  = (unsigned short*)C2;
#pragma unroll
        for (int i = 0; i < 4; ++i)
#pragma unroll
            for (int j = 0; j < 4; ++j) {
                int row0 = m0 + wr + i * 16 + er;
                int col = n0 + wc + j * 16 + fr;
                if (col < D_INNER) {
                    unsigned short o[4];
#pragma unroll
                    for (int r = 0; r < 4; ++r) o[r] = f2b(acc[i][j][r]);
                    *(unsigned long long*)(xiT + (size_t)col * NTOK + row0) = *(unsigned long long*)o;
                } else {
#pragma unroll
                    for (int r = 0; r < 4; ++r)
                        zR[(size_t)(row0 + r) * D_INNER + col - D_INNER] = f2b(acc[i][j][r]);
                }
            }
    } else if (EPI == 1) {
        const unsigned short* uR = (const unsigned short*)res;   // u_row bf16 [t][d]
        unsigned int* dduP = (unsigned int*)C;
        unsigned short* uDP = (unsigned short*)C2;
#pragma unroll
        for (int i = 0; i < 4; ++i)
#pragma unroll
            for (int j = 0; j < 4; ++j) {
                int row0 = m0 + wr + i * 16 + er;
                int col = n0 + wc + j * 16 + fr;
                float bb = bias[col];
                float Dv = aux[col];
#pragma unroll
                for (int r = 0; r < 4; ++r) {
                    size_t idx = (size_t)(row0 + r) * D_INNER + col;
                    float t = acc[i][j][r] + bb;
                    float v = fmaxf(t, 0.f) + log1pf(expf(-fabsf(t)));   // softplus
                    float uf = b2f(uR[idx]);
                    dduP[idx] = ((unsigned)f2b(v)) | (((unsigned)f2b(v * uf)) << 16);
                    uDP[idx] = f2b(uf * Dv);
                }
            }
    } else {
        float* Cs = (float*)C + (size_t)blockIdx.z * M * ldc;
#pragma unroll
        for (int i = 0; i < 4; ++i)
#pragma unroll
            for (int j = 0; j < 4; ++j) {
                int col = n0 + wc + j * 16 + fr;
                if (col < N) {
#pragma unroll
                    for (int r = 0; r < 4; ++r) {
                        int row = m0 + wr + i * 16 + er + r;
                        Cs[(size_t)row * ldc + col] = acc[i][j][r];
                    }
                }
            }
    }
}

// ---------------- out_proj split-K combine + residual ----------------
__global__ void combine_residual(const float* __restrict__ part, const float* __restrict__ x,
                                 float* __restrict__ out) {
    int i = blockIdx.x * 256 + threadIdx.x;
    f32x4 s = *(const f32x4*)(x + (size_t)i * 4);
#pragma unroll
    for (int z = 0; z < 4; ++z)
        s += *(const f32x4*)(part + (size_t)z * NTOK * DIMX + (size_t)i * 4);
    *(f32x4*)(out + (size_t)i * 4) = s;
}

// ---------------- x_proj split-K combine ----------------
__global__ void xproj_combine(const float* __restrict__ xp, unsigned short* __restrict__ xdbl_b,
                              float* __restrict__ B_T, float* __restrict__ C_T) {
    int row = blockIdx.x;
    int col = threadIdx.x;
    if (col >= 96) return;
    float s = 0.f;
#pragma unroll
    for (int p = 0; p < 8; ++p) s += xp[(size_t)p * NTOK * 96 + (size_t)row * 96 + col];
    if (col < 64) xdbl_b[row * 64 + col] = f2b(s);
    else if (col < 80) B_T[(size_t)(col - 64) * NTOK + row] = s;
    else C_T[(size_t)(col - 80) * NTOK + row] = s;
}

// ================= Chunked selective scan: lane = channel, states in registers =================
// Pr eliminated algebraically: Pc[s] = exp2(A2[s] * sum(delta)).

__global__ __launch_bounds__(256) void scan_pass1(
    const unsigned int* __restrict__ ddu, const float* __restrict__ B_T,
    const float* __restrict__ A_log, float* __restrict__ hl, float* __restrict__ Pc) {
    __shared__ float bs[LC][20];               // 16B-aligned rows for b128 broadcast reads
    const int tid = threadIdx.x;
    const int chunk = blockIdx.x;
    const int gchan = blockIdx.y * 256 + tid;
    const int b = gchan >> 11, d = gchan & (D_INNER - 1);
    const int tb = b * L_SEQ + chunk * LC;
    for (int v = tid; v < LC * 16; v += 256) {
        int t = v & (LC - 1), s = v >> 5;
        bs[t][s] = B_T[(size_t)s * NTOK + tb + t];
    }
    __syncthreads();
    float A2[D_STATE], h[D_STATE];
    const float* al = A_log + d * D_STATE;
#pragma unroll
    for (int s = 0; s < D_STATE; ++s) { A2[s] = -__expf(al[s]) * LOG2E; h[s] = 0.f; }
    float dsum = 0.f;
    const unsigned int* pd = ddu + (size_t)tb * D_INNER + d;
    unsigned int pf[8];
#pragma unroll
    for (int t = 0; t < 8; ++t) pf[t] = pd[(size_t)t * D_INNER];
#pragma unroll
    for (int t = 0; t < LC; ++t) {
        unsigned int v = pf[t & 7];
        if (t + 8 < LC) pf[t & 7] = pd[(size_t)(t + 8) * D_INNER];
        float dl = lo2f(v), du = hi2f(v);
        dsum += dl;
#pragma unroll
        for (int i = 0; i < 4; ++i) {
            f32x4 bv = *(const f32x4*)&bs[t][4 * i];
#pragma unroll
            for (int q = 0; q < 4; ++q) {
                int s = 4 * i + q;
                float e = exp2f(dl * A2[s]);
                h[s] = e * h[s] + du * bv[q];
            }
        }
    }
    float* ph = hl + (size_t)chunk * NLANE + (size_t)gchan * D_STATE;
    float* pp = Pc + (size_t)chunk * NLANE + (size_t)gchan * D_STATE;
#pragma unroll
    for (int q = 0; q < 4; ++q) {
        f32x4 hv = {h[4 * q], h[4 * q + 1], h[4 * q + 2], h[4 * q + 3]};
        f32x4 pv = {exp2f(dsum * A2[4 * q]),     exp2f(dsum * A2[4 * q + 1]),
                    exp2f(dsum * A2[4 * q + 2]), exp2f(dsum * A2[4 * q + 3])};
        *(f32x4*)(ph + 4 * q) = hv;
        *(f32x4*)(pp + 4 * q) = pv;
    }
}

__global__ __launch_bounds__(256) void scan_pass2(const float* __restrict__ hl,
                                                  const float* __restrict__ Pc,
                                                  float* __restrict__ hi) {
    int gid = blockIdx.x * 256 + threadIdx.x;
    float h = 0.f;
    hi[gid] = 0.f;
#pragma unroll
    for (int c = 1; c < NC; ++c) {
        h = hl[(size_t)(c - 1) * NLANE + gid] + Pc[(size_t)(c - 1) * NLANE + gid] * h;
        hi[(size_t)c * NLANE + gid] = h;
    }
}

__global__ __launch_bounds__(256) void scan_pass3(
    const unsigned int* __restrict__ ddu, const float* __restrict__ B_T,
    const float* __restrict__ C_T, const unsigned short* __restrict__ uD,
    const unsigned short* __restrict__ z_row, const float* __restrict__ A_log,
    const float* __restrict__ hi, unsigned short* __restrict__ y_row) {
    __shared__ float bcs[LC][36];              // [t][0..15]=B, [t][16..31]=C (16B-aligned rows)
    const int tid = threadIdx.x;
    const int chunk = blockIdx.x;
    const int gchan = blockIdx.y * 256 + tid;
    const int b = gchan >> 11, d = gchan & (D_INNER - 1);
    const int tb = b * L_SEQ + chunk * LC;
    for (int v = tid; v < LC * 32; v += 256) {
        int t = v & (LC - 1), q = v >> 5;
        bcs[t][q] = (q < 16) ? B_T[(size_t)q * NTOK + tb + t]
                             : C_T[(size_t)(q - 16) * NTOK + tb + t];
    }
    __syncthreads();
    float A2[D_STATE], h[D_STATE];
    const float* al = A_log + d * D_STATE;
#pragma unroll
    for (int s = 0; s < D_STATE; ++s) A2[s] = -__expf(al[s]) * LOG2E;
    const float* ph = hi + (size_t)chunk * NLANE + (size_t)gchan * D_STATE;
#pragma unroll
    for (int q = 0; q < 4; ++q) {
        f32x4 hv = *(const f32x4*)(ph + 4 * q);
#pragma unroll
        for (int r = 0; r < 4; ++r) h[4 * q + r] = hv[r];
    }
    const unsigned int* pd = ddu + (size_t)tb * D_INNER + d;
    const unsigned short* pu = uD + (size_t)tb * D_INNER + d;
    const unsigned short* pz = z_row + (size_t)tb * D_INNER + d;
    unsigned short* py = y_row + (size_t)tb * D_INNER + d;
    unsigned int pf[4];
    unsigned short pfu[4], pfz[4];
#pragma unroll
    for (int t = 0; t < 4; ++t) {
        pf[t] = pd[(size_t)t * D_INNER];
        pfu[t] = pu[(size_t)t * D_INNER];
        pfz[t] = pz[(size_t)t * D_INNER];
    }
#pragma unroll
    for (int t = 0; t < LC; ++t) {
        unsigned int v = pf[t & 3];
        float uDv = b2f(pfu[t & 3]);
        float zz = b2f(pfz[t & 3]);
        if (t + 4 < LC) {
            pf[t & 3] = pd[(size_t)(t + 4) * D_INNER];
            pfu[t & 3] = pu[(size_t)(t + 4) * D_INNER];
            pfz[t & 3] = pz[(size_t)(t + 4) * D_INNER];
        }
        float dl = lo2f(v), du = hi2f(v);
        float y0 = 0.f, y1 = 0.f, y2 = 0.f, y3 = 0.f;
#pragma unroll
        for (int i = 0; i < 4; ++i) {
            f32x4 bv = *(const f32x4*)&bcs[t][4 * i];
            f32x4 cv = *(const f32x4*)&bcs[t][16 + 4 * i];
#pragma unroll
            for (int q = 0; q < 4; ++q) {
                int s = 4 * i + q;
                float e = exp2f(dl * A2[s]);
                h[s] = e * h[s] + du * bv[q];
                float yv = h[s] * cv[q];
                if (q == 0) y0 += yv;
                else if (q == 1) y1 += yv;
                else if (q == 2) y2 += yv;
                else y3 += yv;
            }
        }
        float y = (y0 + y1) + (y2 + y3);
        float yy = y + uDv;
        py[(size_t)t * D_INNER] = f2b(yy * (zz / (1.f + __expf(-zz))));
    }
}

extern "C" void kernel_launch(void* const* d_in, const int* in_sizes, int n_in,
                              void* d_out, int out_size, void* d_ws, size_t ws_size,
                              hipStream_t stream) {
    const float* x          = (const float*)d_in[0];
    const float* norm_w     = (const float*)d_in[1];
    const float* in_proj_w  = (const float*)d_in[2];
    const float* conv_w     = (const float*)d_in[3];
    const float* conv_b     = (const float*)d_in[4];
    const float* x_proj_w   = (const float*)d_in[5];
    const float* dt_proj_w  = (const float*)d_in[6];
    const float* dt_proj_b  = (const float*)d_in[7];
    const float* A_log      = (const float*)d_in[8];
    const float* D_param    = (const float*)d_in[9];
    const float* out_proj_w = (const float*)d_in[10];
    float* out = (float*)d_out;

    char* p = (char*)d_ws;
    unsigned short* xi_T  = (unsigned short*)p; p += (size_t)D_INNER * NTOK * 2;   // 8.39 MB
    unsigned short* z_row = (unsigned short*)p; p += (size_t)NTOK * D_INNER * 2;   // 8.39 MB
    unsigned int*   ddu   = (unsigned int*)p;   p += (size_t)NTOK * D_INNER * 4;   // 16.78 MB
    unsigned short* u_row = (unsigned short*)p; p += (size_t)NTOK * D_INNER * 2;   // 8.39 MB
    unsigned short* uD    = (unsigned short*)p; p += (size_t)NTOK * D_INNER * 2;   // 8.39 MB
    unsigned short* y_row = (unsigned short*)p; p += (size_t)NTOK * D_INNER * 2;   // 8.39 MB
    unsigned short* xdbl_b = (unsigned short*)p; p += (size_t)NTOK * 64 * 2;       // 0.26 MB
    float* B_T = (float*)p;  p += (size_t)D_STATE * NTOK * 4;                      // 0.13 MB
    float* C_T = (float*)p;  p += (size_t)D_STATE * NTOK * 4;                      // 0.13 MB
    unsigned short* xn_b = (unsigned short*)p; p += (size_t)NTOK * DIMX * 2;       // 4.19 MB
    unsigned short* w_in_b  = (unsigned short*)p; p += (size_t)2 * D_INNER * DIMX * 2;  // 8.39 MB
    unsigned short* w_x_b   = (unsigned short*)p; p += (size_t)96 * D_INNER * 2;
    unsigned short* w_dt_b  = (unsigned short*)p; p += (size_t)D_INNER * DT_RANK * 2;
    unsigned short* w_out_b = (unsigned short*)p; p += (size_t)DIMX * D_INNER * 2;

    // overlays (disjoint lifetimes):
    float* xp_part = (float*)y_row;            // 6.29 MB (y_row written only by pass3)
    float* hl = (float*)u_row;                 // 8.39 MB (u_row dead after dt_proj; pass1+)
    float* Pc = (float*)w_in_b;                // 8.39 MB (w_in dead after in_proj; pass1+)
    float* hi = (float*)xi_T;                  // 8.39 MB (xi_T dead after conv; pass2+)
    float* out_part = (float*)ddu;             // 33.5 MB = ddu + u_row(hl) + uD (dead after pass3)

    // 0. all weight conversions f32 -> bf16 (one kernel)
    f2b_all<<<(N1C + N2C + N3C + N4C + 255) / 256, 256, 0, stream>>>(
        in_proj_w, x_proj_w, dt_proj_w, out_proj_w, w_in_b, w_x_b, w_dt_b, w_out_b);

    // 1. RMSNorm -> bf16
    rmsnorm_kernel<<<NTOK, 256, 0, stream>>>(x, norm_w, xn_b);
    // 2. in_proj: xi_T bf16 [d][t] + z_row bf16 [t][d]
    gemm_mfma<3><<<dim3(32, 16), 256, 0, stream>>>(xn_b, w_in_b, xi_T, z_row,
        NTOK, 2 * D_INNER, DIMX, DIMX, DIMX, NTOK, nullptr, nullptr, nullptr);
    // 3. FUSED conv + SiLU -> u_row [t][d]
    conv_silu_tr<<<dim3(NTOK / 64, D_INNER / 64), 256, 0, stream>>>(
        xi_T, conv_w, conv_b, u_row);
    // 4. x_proj split-K=8 partials + combine
    gemm_mfma<0><<<dim3(1, 16, 8), 256, 0, stream>>>(u_row, w_x_b, xp_part, nullptr,
        NTOK, 96, D_INNER, D_INNER, D_INNER, 96, nullptr, nullptr, nullptr);
    xproj_combine<<<NTOK, 128, 0, stream>>>(xp_part, xdbl_b, B_T, C_T);
    // 5. dt_proj: ddu [t][d] (packed bf16 delta,du) + uD [t][d] (u*D)
    gemm_mfma<1><<<dim3(16, 16), 256, 0, stream>>>(xdbl_b, w_dt_b, ddu, uD,
        NTOK, D_INNER, DT_RANK, 64, DT_RANK, D_INNER, dt_proj_b, (const float*)u_row, D_param);
    // 6. chunked selective scan (lane=channel, states in registers)
    scan_pass1<<<dim3(NC, NCH / 256), 256, 0, stream>>>(ddu, B_T, A_log, hl, Pc);
    scan_pass2<<<NLANE / 256, 256, 0, stream>>>(hl, Pc, hi);
    scan_pass3<<<dim3(NC, NCH / 256), 256, 0, stream>>>(ddu, B_T, C_T, uD, z_row, A_log, hi, y_row);
    // 7. out_proj split-K=4 -> partials (ddu/hl/uD region dead after pass3)
    gemm_mfma<0><<<dim3(8, 16, 4), 256, 0, stream>>>(y_row, w_out_b, out_part, nullptr,
        NTOK, DIMX, D_INNER, D_INNER, D_INNER, DIMX, nullptr, nullptr, nullptr);
    // 8. combine partials + residual -> out
    combine_residual<<<NTOK * DIMX / 4 / 256, 256, 0, stream>>>(out_part, x, out);
}

// Round 19
// 173.763 us; speedup vs baseline: 1.5299x; 1.0805x over previous
//
#include <hip/hip_runtime.h>
#include <math.h>

#define DIMX 1024
#define D_STATE 16
#define D_INNER 2048
#define DT_RANK 64
#define B_SZ 2
#define L_SEQ 1024
#define NTOK (B_SZ * L_SEQ)
#define EPSR 1e-5f
#define NC 32          // chunks per sequence
#define LC 32          // steps per chunk
#define NCH (B_SZ * D_INNER)            // 4096 channels
#define NLANE (NCH * D_STATE)           // 65536 (chan,state) pairs
#define LOG2E 1.44269504f

typedef __attribute__((ext_vector_type(8))) short bf16x8;
typedef __attribute__((ext_vector_type(4))) int   i32x4;
typedef __attribute__((ext_vector_type(4))) float f32x4;
typedef __attribute__((ext_vector_type(4))) unsigned short u16x4;

__device__ __forceinline__ unsigned short f2b(float f) {
    unsigned int u = __builtin_bit_cast(unsigned int, f);
    u += 0x7fffu + ((u >> 16) & 1u);          // RNE
    return (unsigned short)(u >> 16);
}
__device__ __forceinline__ float b2f(unsigned short h) {
    unsigned int u = ((unsigned int)h) << 16;
    return __builtin_bit_cast(float, u);
}
__device__ __forceinline__ float lo2f(unsigned int v) {       // low bf16 -> f32
    return __builtin_bit_cast(float, v << 16);
}
__device__ __forceinline__ float hi2f(unsigned int v) {       // high bf16 -> f32
    return __builtin_bit_cast(float, v & 0xffff0000u);
}
// async global->LDS, 16B per lane, wave-uniform LDS base + lane*16
__device__ __forceinline__ void gload16(const void* g, void* l) {
    __builtin_amdgcn_global_load_lds(
        (const __attribute__((address_space(1))) unsigned int*)g,
        (__attribute__((address_space(3))) unsigned int*)l, 16, 0, 0);
}

// ---------------- fused prep: all weight f32->bf16 conversions + RMSNorm ----------------
#define N1C (2 * D_INNER * DIMX / 4)
#define N2C (96 * D_INNER / 4)
#define N3C (D_INNER * DT_RANK / 4)
#define N4C (DIMX * D_INNER / 4)
#define NWCONV ((N1C + N2C + N3C + N4C + 255) / 256)
__global__ __launch_bounds__(256) void prep_kernel(
    const float* __restrict__ w_in, const float* __restrict__ w_x,
    const float* __restrict__ w_dt, const float* __restrict__ w_out,
    const float* __restrict__ x, const float* __restrict__ norm_w,
    unsigned short* __restrict__ o_in, unsigned short* __restrict__ o_x,
    unsigned short* __restrict__ o_dt, unsigned short* __restrict__ o_out,
    unsigned short* __restrict__ xnb) {
    if ((int)blockIdx.x < NWCONV) {
        int i = blockIdx.x * 256 + threadIdx.x;
        const float* src; unsigned short* dst; int j;
        if (i < N1C)                        { src = w_in;  dst = o_in;  j = i; }
        else if (i < N1C + N2C)             { src = w_x;   dst = o_x;   j = i - N1C; }
        else if (i < N1C + N2C + N3C)       { src = w_dt;  dst = o_dt;  j = i - N1C - N2C; }
        else if (i < N1C + N2C + N3C + N4C) { src = w_out; dst = o_out; j = i - N1C - N2C - N3C; }
        else return;
        f32x4 v = *(const f32x4*)(src + (size_t)j * 4);
        unsigned short o[4];
#pragma unroll
        for (int k = 0; k < 4; ++k) o[k] = f2b(v[k]);
        *(unsigned long long*)(dst + (size_t)j * 4) = *(unsigned long long*)o;
    } else {
        int row = blockIdx.x - NWCONV;
        const float* xr = x + (size_t)row * DIMX;
        unsigned short* outr = xnb + (size_t)row * DIMX;
        int t = threadIdx.x;
        float v[4];
        float ss = 0.f;
#pragma unroll
        for (int i = 0; i < 4; ++i) { v[i] = xr[t + i * 256]; ss += v[i] * v[i]; }
#pragma unroll
        for (int off = 32; off > 0; off >>= 1) ss += __shfl_down(ss, off);
        __shared__ float red[4];
        if ((t & 63) == 0) red[t >> 6] = ss;
        __syncthreads();
        float tot = red[0] + red[1] + red[2] + red[3];
        float scale = rsqrtf(tot * (1.f / DIMX) + EPSR);
#pragma unroll
        for (int i = 0; i < 4; ++i) outr[t + i * 256] = f2b(v[i] * scale * norm_w[t + i * 256]);
    }
}

// ---------------- FUSED depthwise causal conv + SiLU, row-major in/out [t][d] ----------------
__global__ __launch_bounds__(256) void conv_silu_row(
    const unsigned short* __restrict__ xiR, const float* __restrict__ cw,
    const float* __restrict__ cb, unsigned short* __restrict__ u_row) {
    __shared__ unsigned int xs[67 * 65];       // [t_local 0..66][d 0..63], t = t0-3+row
    __shared__ unsigned int ob[64 * 65];
    const int t0 = blockIdx.x * 64;
    const int d0 = blockIdx.y * 64;
    const int bstart = t0 & ~(L_SEQ - 1);
    const int tid = threadIdx.x;
    for (int task = tid; task < 536; task += 256) {   // 67 rows x 8 chunks of 8 channels
        int row = task >> 3, c8 = (task & 7) * 8;
        int t = t0 - 3 + row;
        if (t >= bstart) {
            i32x4 v = *(const i32x4*)(xiR + (size_t)t * D_INNER + d0 + c8);
            const unsigned short* vs = (const unsigned short*)&v;
#pragma unroll
            for (int i = 0; i < 8; ++i)
                xs[row * 65 + c8 + i] = __builtin_bit_cast(unsigned int, b2f(vs[i]));
        } else {
#pragma unroll
            for (int i = 0; i < 8; ++i) xs[row * 65 + c8 + i] = 0u;
        }
    }
    __syncthreads();
    {
        const int dl = tid & 63, tr = tid >> 6;
        const int d = d0 + dl, lt0 = tr * 16;
        const float w0 = cw[d * 4 + 0], w1 = cw[d * 4 + 1], w2 = cw[d * 4 + 2], w3 = cw[d * 4 + 3];
        const float bias = cb[d];
        float x0 = __builtin_bit_cast(float, xs[(lt0 + 0) * 65 + dl]);
        float x1 = __builtin_bit_cast(float, xs[(lt0 + 1) * 65 + dl]);
        float x2 = __builtin_bit_cast(float, xs[(lt0 + 2) * 65 + dl]);
#pragma unroll
        for (int i = 0; i < 16; ++i) {
            float x3 = __builtin_bit_cast(float, xs[(lt0 + 3 + i) * 65 + dl]);
            float a = bias + w0 * x0 + w1 * x1 + w2 * x2 + w3 * x3;
            ob[(lt0 + i) * 65 + dl] = f2b(a / (1.f + __expf(-a)));
            x0 = x1; x1 = x2; x2 = x3;
        }
    }
    __syncthreads();
#pragma unroll
    for (int it = 0; it < 2; ++it) {
        int k = tid + it * 256;
        int t = k >> 3, d8 = (k & 7) * 8;
        unsigned short o[8];
#pragma unroll
        for (int j = 0; j < 8; ++j) o[j] = (unsigned short)ob[t * 65 + d8 + j];
        *(i32x4*)(u_row + (size_t)(t0 + t) * D_INNER + d0 + d8) = *(const i32x4*)o;
    }
}

// ---------------- bf16 MFMA GEMM with global_load_lds staging ----------------
// EPI 0: row-major f32 partial store (split-K via blockIdx.z plane offset)
// EPI 1: dt_proj: delta=softplus(acc+bias[col]); ddu[t][d]=pack(delta,delta*u); uD[t][d]=u*D
// EPI 3: in_proj: col<2048 -> xi_row [t][d]; col>=2048 -> z_row [t][d]  (both coalesced)
template <int EPI>
__global__ __launch_bounds__(256) void gemm_mfma(
    const unsigned short* __restrict__ A, const unsigned short* __restrict__ B,
    void* __restrict__ C, void* __restrict__ C2,
    int M, int N, int K, int lda, int ldb, int ldc,
    const float* __restrict__ bias, const float* __restrict__ res,
    const float* __restrict__ aux) {
    __shared__ unsigned short As[128 * 32];
    __shared__ unsigned short Bs[128 * 32];
    const int tid = threadIdx.x;
    const int m0 = blockIdx.y * 128, n0 = blockIdx.x * 128;
    const int lane = tid & 63, wave = tid >> 6;
    const int wr = (wave >> 1) * 64, wc = (wave & 1) * 64;
    const int fr = lane & 15, fk = (lane >> 4) * 8;
    const int kspan = K / gridDim.z;
    const int kb = blockIdx.z * kspan;
    const int srow = lane >> 2, sc8 = (lane & 3) * 8;
    f32x4 acc[4][4] = {};
    for (int k0 = kb; k0 < kb + kspan; k0 += 32) {
#pragma unroll
        for (int i = 0; i < 2; ++i) {
            int q = wave + 4 * i;
            int row = q * 16 + srow;
            gload16(A + (size_t)(m0 + row) * lda + k0 + sc8, (unsigned short*)As + q * 512);
            gload16(B + (size_t)(n0 + row) * ldb + k0 + sc8, (unsigned short*)Bs + q * 512);
        }
        __syncthreads();
        bf16x8 af[4], bfr[4];
#pragma unroll
        for (int i = 0; i < 4; ++i) af[i]  = *(const bf16x8*)&As[(wr + i * 16 + fr) * 32 + fk];
#pragma unroll
        for (int j = 0; j < 4; ++j) bfr[j] = *(const bf16x8*)&Bs[(wc + j * 16 + fr) * 32 + fk];
#pragma unroll
        for (int i = 0; i < 4; ++i)
#pragma unroll
            for (int j = 0; j < 4; ++j)
                acc[i][j] = __builtin_amdgcn_mfma_f32_16x16x32_bf16(af[i], bfr[j], acc[i][j], 0, 0, 0);
        __syncthreads();
    }
    const int er = (lane >> 4) * 4;
    if (EPI == 3) {
        unsigned short* xiR = (unsigned short*)C;
        unsigned short* zR  = (unsigned short*)C2;
#pragma unroll
        for (int i = 0; i < 4; ++i)
#pragma unroll
            for (int j = 0; j < 4; ++j) {
                int row0 = m0 + wr + i * 16 + er;
                int col = n0 + wc + j * 16 + fr;
                unsigned short* dst;
                int colm;
                if (col < D_INNER) { dst = xiR; colm = col; }
                else               { dst = zR;  colm = col - D_INNER; }
#pragma unroll
                for (int r = 0; r < 4; ++r)
                    dst[(size_t)(row0 + r) * D_INNER + colm] = f2b(acc[i][j][r]);
            }
    } else if (EPI == 1) {
        const unsigned short* uR = (const unsigned short*)res;   // u_row bf16 [t][d]
        unsigned int* dduP = (unsigned int*)C;
        unsigned short* uDP = (unsigned short*)C2;
#pragma unroll
        for (int i = 0; i < 4; ++i)
#pragma unroll
            for (int j = 0; j < 4; ++j) {
                int row0 = m0 + wr + i * 16 + er;
                int col = n0 + wc + j * 16 + fr;
                float bb = bias[col];
                float Dv = aux[col];
#pragma unroll
                for (int r = 0; r < 4; ++r) {
                    size_t idx = (size_t)(row0 + r) * D_INNER + col;
                    float t = acc[i][j][r] + bb;
                    float v = fmaxf(t, 0.f) + __logf(1.f + __expf(-fabsf(t)));   // fast softplus
                    float uf = b2f(uR[idx]);
                    dduP[idx] = ((unsigned)f2b(v)) | (((unsigned)f2b(v * uf)) << 16);
                    uDP[idx] = f2b(uf * Dv);
                }
            }
    } else {
        float* Cs = (float*)C + (size_t)blockIdx.z * M * ldc;
#pragma unroll
        for (int i = 0; i < 4; ++i)
#pragma unroll
            for (int j = 0; j < 4; ++j) {
                int col = n0 + wc + j * 16 + fr;
                if (col < N) {
#pragma unroll
                    for (int r = 0; r < 4; ++r) {
                        int row = m0 + wr + i * 16 + er + r;
                        Cs[(size_t)row * ldc + col] = acc[i][j][r];
                    }
                }
            }
    }
}

// ---------------- out_proj split-K=2 combine + residual ----------------
__global__ void combine_residual(const float* __restrict__ part, const float* __restrict__ x,
                                 float* __restrict__ out) {
    int i = blockIdx.x * 256 + threadIdx.x;
    f32x4 s = *(const f32x4*)(x + (size_t)i * 4);
#pragma unroll
    for (int z = 0; z < 2; ++z)
        s += *(const f32x4*)(part + (size_t)z * NTOK * DIMX + (size_t)i * 4);
    *(f32x4*)(out + (size_t)i * 4) = s;
}

// ---------------- x_proj split-K combine ----------------
__global__ void xproj_combine(const float* __restrict__ xp, unsigned short* __restrict__ xdbl_b,
                              float* __restrict__ B_T, float* __restrict__ C_T) {
    int row = blockIdx.x;
    int col = threadIdx.x;
    if (col >= 96) return;
    float s = 0.f;
#pragma unroll
    for (int p = 0; p < 8; ++p) s += xp[(size_t)p * NTOK * 96 + (size_t)row * 96 + col];
    if (col < 64) xdbl_b[row * 64 + col] = f2b(s);
    else if (col < 80) B_T[(size_t)(col - 64) * NTOK + row] = s;
    else C_T[(size_t)(col - 80) * NTOK + row] = s;
}

// ================= Chunked selective scan: lane = channel, states in registers =================

__global__ __launch_bounds__(256) void scan_pass1(
    const unsigned int* __restrict__ ddu, const float* __restrict__ B_T,
    const float* __restrict__ A_log, float* __restrict__ hl, float* __restrict__ Pc) {
    __shared__ float bs[LC][20];
    const int tid = threadIdx.x;
    const int chunk = blockIdx.x;
    const int gchan = blockIdx.y * 256 + tid;
    const int b = gchan >> 11, d = gchan & (D_INNER - 1);
    const int tb = b * L_SEQ + chunk * LC;
    for (int v = tid; v < LC * 16; v += 256) {
        int t = v & (LC - 1), s = v >> 5;
        bs[t][s] = B_T[(size_t)s * NTOK + tb + t];
    }
    __syncthreads();
    float A2[D_STATE], h[D_STATE];
    const float* al = A_log + d * D_STATE;
#pragma unroll
    for (int s = 0; s < D_STATE; ++s) { A2[s] = -__expf(al[s]) * LOG2E; h[s] = 0.f; }
    float dsum = 0.f;
    const unsigned int* pd = ddu + (size_t)tb * D_INNER + d;
    unsigned int pf[8];
#pragma unroll
    for (int t = 0; t < 8; ++t) pf[t] = pd[(size_t)t * D_INNER];
#pragma unroll
    for (int t = 0; t < LC; ++t) {
        unsigned int v = pf[t & 7];
        if (t + 8 < LC) pf[t & 7] = pd[(size_t)(t + 8) * D_INNER];
        float dl = lo2f(v), du = hi2f(v);
        dsum += dl;
#pragma unroll
        for (int i = 0; i < 4; ++i) {
            f32x4 bv = *(const f32x4*)&bs[t][4 * i];
#pragma unroll
            for (int q = 0; q < 4; ++q) {
                int s = 4 * i + q;
                float e = exp2f(dl * A2[s]);
                h[s] = e * h[s] + du * bv[q];
            }
        }
    }
    float* ph = hl + (size_t)chunk * NLANE + (size_t)gchan * D_STATE;
    float* pp = Pc + (size_t)chunk * NLANE + (size_t)gchan * D_STATE;
#pragma unroll
    for (int q = 0; q < 4; ++q) {
        f32x4 hv = {h[4 * q], h[4 * q + 1], h[4 * q + 2], h[4 * q + 3]};
        f32x4 pv = {exp2f(dsum * A2[4 * q]),     exp2f(dsum * A2[4 * q + 1]),
                    exp2f(dsum * A2[4 * q + 2]), exp2f(dsum * A2[4 * q + 3])};
        *(f32x4*)(ph + 4 * q) = hv;
        *(f32x4*)(pp + 4 * q) = pv;
    }
}

__global__ __launch_bounds__(256) void scan_pass2(const float* __restrict__ hl,
                                                  const float* __restrict__ Pc,
                                                  float* __restrict__ hi) {
    int gid = blockIdx.x * 256 + threadIdx.x;
    float h = 0.f;
    hi[gid] = 0.f;
#pragma unroll
    for (int c = 1; c < NC; ++c) {
        h = hl[(size_t)(c - 1) * NLANE + gid] + Pc[(size_t)(c - 1) * NLANE + gid] * h;
        hi[(size_t)c * NLANE + gid] = h;
    }
}

__global__ __launch_bounds__(256) void scan_pass3(
    const unsigned int* __restrict__ ddu, const float* __restrict__ B_T,
    const float* __restrict__ C_T, const unsigned short* __restrict__ uD,
    const unsigned short* __restrict__ z_row, const float* __restrict__ A_log,
    const float* __restrict__ hi, unsigned short* __restrict__ y_row) {
    __shared__ float bcs[LC][36];
    const int tid = threadIdx.x;
    const int chunk = blockIdx.x;
    const int gchan = blockIdx.y * 256 + tid;
    const int b = gchan >> 11, d = gchan & (D_INNER - 1);
    const int tb = b * L_SEQ + chunk * LC;
    for (int v = tid; v < LC * 32; v += 256) {
        int t = v & (LC - 1), q = v >> 5;
        bcs[t][q] = (q < 16) ? B_T[(size_t)q * NTOK + tb + t]
                             : C_T[(size_t)(q - 16) * NTOK + tb + t];
    }
    __syncthreads();
    float A2[D_STATE], h[D_STATE];
    const float* al = A_log + d * D_STATE;
#pragma unroll
    for (int s = 0; s < D_STATE; ++s) A2[s] = -__expf(al[s]) * LOG2E;
    const float* ph = hi + (size_t)chunk * NLANE + (size_t)gchan * D_STATE;
#pragma unroll
    for (int q = 0; q < 4; ++q) {
        f32x4 hv = *(const f32x4*)(ph + 4 * q);
#pragma unroll
        for (int r = 0; r < 4; ++r) h[4 * q + r] = hv[r];
    }
    const unsigned int* pd = ddu + (size_t)tb * D_INNER + d;
    const unsigned short* pu = uD + (size_t)tb * D_INNER + d;
    const unsigned short* pz = z_row + (size_t)tb * D_INNER + d;
    unsigned short* py = y_row + (size_t)tb * D_INNER + d;
    unsigned int pf[4];
    unsigned short pfu[4], pfz[4];
#pragma unroll
    for (int t = 0; t < 4; ++t) {
        pf[t] = pd[(size_t)t * D_INNER];
        pfu[t] = pu[(size_t)t * D_INNER];
        pfz[t] = pz[(size_t)t * D_INNER];
    }
#pragma unroll
    for (int t = 0; t < LC; ++t) {
        unsigned int v = pf[t & 3];
        float uDv = b2f(pfu[t & 3]);
        float zz = b2f(pfz[t & 3]);
        if (t + 4 < LC) {
            pf[t & 3] = pd[(size_t)(t + 4) * D_INNER];
            pfu[t & 3] = pu[(size_t)(t + 4) * D_INNER];
            pfz[t & 3] = pz[(size_t)(t + 4) * D_INNER];
        }
        float dl = lo2f(v), du = hi2f(v);
        float y0 = 0.f, y1 = 0.f, y2 = 0.f, y3 = 0.f;
#pragma unroll
        for (int i = 0; i < 4; ++i) {
            f32x4 bv = *(const f32x4*)&bcs[t][4 * i];
            f32x4 cv = *(const f32x4*)&bcs[t][16 + 4 * i];
#pragma unroll
            for (int q = 0; q < 4; ++q) {
                int s = 4 * i + q;
                float e = exp2f(dl * A2[s]);
                h[s] = e * h[s] + du * bv[q];
                float yv = h[s] * cv[q];
                if (q == 0) y0 += yv;
                else if (q == 1) y1 += yv;
                else if (q == 2) y2 += yv;
                else y3 += yv;
            }
        }
        float y = (y0 + y1) + (y2 + y3);
        float yy = y + uDv;
        py[(size_t)t * D_INNER] = f2b(yy * (zz / (1.f + __expf(-zz))));
    }
}

extern "C" void kernel_launch(void* const* d_in, const int* in_sizes, int n_in,
                              void* d_out, int out_size, void* d_ws, size_t ws_size,
                              hipStream_t stream) {
    const float* x          = (const float*)d_in[0];
    const float* norm_w     = (const float*)d_in[1];
    const float* in_proj_w  = (const float*)d_in[2];
    const float* conv_w     = (const float*)d_in[3];
    const float* conv_b     = (const float*)d_in[4];
    const float* x_proj_w   = (const float*)d_in[5];
    const float* dt_proj_w  = (const float*)d_in[6];
    const float* dt_proj_b  = (const float*)d_in[7];
    const float* A_log      = (const float*)d_in[8];
    const float* D_param    = (const float*)d_in[9];
    const float* out_proj_w = (const float*)d_in[10];
    float* out = (float*)d_out;

    char* p = (char*)d_ws;
    unsigned short* xi_row = (unsigned short*)p; p += (size_t)NTOK * D_INNER * 2;  // 8.39 MB
    unsigned short* z_row  = (unsigned short*)p; p += (size_t)NTOK * D_INNER * 2;  // 8.39 MB
    unsigned int*   ddu    = (unsigned int*)p;   p += (size_t)NTOK * D_INNER * 4;  // 16.78 MB
    unsigned short* u_row  = (unsigned short*)p; p += (size_t)NTOK * D_INNER * 2;  // 8.39 MB
    unsigned short* uD     = (unsigned short*)p; p += (size_t)NTOK * D_INNER * 2;  // 8.39 MB
    unsigned short* y_row  = (unsigned short*)p; p += (size_t)NTOK * D_INNER * 2;  // 8.39 MB
    unsigned short* xdbl_b = (unsigned short*)p; p += (size_t)NTOK * 64 * 2;       // 0.26 MB
    float* B_T = (float*)p;  p += (size_t)D_STATE * NTOK * 4;                      // 0.13 MB
    float* C_T = (float*)p;  p += (size_t)D_STATE * NTOK * 4;                      // 0.13 MB
    unsigned short* xn_b = (unsigned short*)p; p += (size_t)NTOK * DIMX * 2;       // 4.19 MB
    unsigned short* w_in_b  = (unsigned short*)p; p += (size_t)2 * D_INNER * DIMX * 2;  // 8.39 MB
    unsigned short* w_x_b   = (unsigned short*)p; p += (size_t)96 * D_INNER * 2;
    unsigned short* w_dt_b  = (unsigned short*)p; p += (size_t)D_INNER * DT_RANK * 2;
    unsigned short* w_out_b = (unsigned short*)p; p += (size_t)DIMX * D_INNER * 2;

    // overlays (disjoint lifetimes):
    float* xp_part = (float*)y_row;            // 6.29 MB (y_row written only by pass3)
    float* hl = (float*)u_row;                 // 8.39 MB (u_row dead after dt_proj; pass1+)
    float* Pc = (float*)w_in_b;                // 8.39 MB (w_in dead after in_proj; pass1+)
    float* hi = (float*)xi_row;                // 8.39 MB (xi_row dead after conv; pass2+)
    float* out_part = (float*)ddu;             // 16.78 MB (split-K=2; ddu dead after pass3)

    // 0. fused prep: weight conversions + RMSNorm
    prep_kernel<<<NWCONV + NTOK, 256, 0, stream>>>(
        in_proj_w, x_proj_w, dt_proj_w, out_proj_w, x, norm_w,
        w_in_b, w_x_b, w_dt_b, w_out_b, xn_b);
    // 1. in_proj: xi_row [t][d] + z_row [t][d]
    gemm_mfma<3><<<dim3(32, 16), 256, 0, stream>>>(xn_b, w_in_b, xi_row, z_row,
        NTOK, 2 * D_INNER, DIMX, DIMX, DIMX, D_INNER, nullptr, nullptr, nullptr);
    // 2. FUSED conv + SiLU -> u_row [t][d]
    conv_silu_row<<<dim3(NTOK / 64, D_INNER / 64), 256, 0, stream>>>(
        xi_row, conv_w, conv_b, u_row);
    // 3. x_proj split-K=8 partials + combine
    gemm_mfma<0><<<dim3(1, 16, 8), 256, 0, stream>>>(u_row, w_x_b, xp_part, nullptr,
        NTOK, 96, D_INNER, D_INNER, D_INNER, 96, nullptr, nullptr, nullptr);
    xproj_combine<<<NTOK, 128, 0, stream>>>(xp_part, xdbl_b, B_T, C_T);
    // 4. dt_proj: ddu [t][d] (packed bf16 delta,du) + uD [t][d] (u*D)
    gemm_mfma<1><<<dim3(16, 16), 256, 0, stream>>>(xdbl_b, w_dt_b, ddu, uD,
        NTOK, D_INNER, DT_RANK, 64, DT_RANK, D_INNER, dt_proj_b, (const float*)u_row, D_param);
    // 5. chunked selective scan (lane=channel, states in registers)
    scan_pass1<<<dim3(NC, NCH / 256), 256, 0, stream>>>(ddu, B_T, A_log, hl, Pc);
    scan_pass2<<<NLANE / 256, 256, 0, stream>>>(hl, Pc, hi);
    scan_pass3<<<dim3(NC, NCH / 256), 256, 0, stream>>>(ddu, B_T, C_T, uD, z_row, A_log, hi, y_row);
    // 6. out_proj split-K=2 -> partials (ddu region dead after pass3)
    gemm_mfma<0><<<dim3(8, 16, 2), 256, 0, stream>>>(y_row, w_out_b, out_part, nullptr,
        NTOK, DIMX, D_INNER, D_INNER, D_INNER, DIMX, nullptr, nullptr, nullptr);
    // 7. combine partials + residual -> out
    combine_residual<<<NTOK * DIMX / 4 / 256, 256, 0, stream>>>(out_part, x, out);
}